// Round 16
// baseline (432.057 us; speedup 1.0000x reference)
//
#include <hip/hip_runtime.h>
#include <hip/hip_fp16.h>

#define N_NODES 50000
#define N_EDGES 1600000
#define F_IN    128
#define EMB     48
#define HID     48
#define OUTF    64
#define KCH     7
#define TPAD    64                   // padded T row length (halves) = 128 B

#define NR    8                      // node ranges (LDS partitions)
#define RANGE (N_NODES / NR)         // 6250 counters
#define BPR   64                     // edge slices
#define SLICE (N_EDGES / BPR)        // 25000 edges per slice (div by 4)
#define HTHREADS 512
#define NBLK  ((N_NODES + 255) / 256)   // 196 reduce blocks
#define NTILES (N_NODES / 16)        // 3125 node tiles

// source-range partition (locality presort)
#define SRSH  13                     // bucket = row >> 13 (8192 nodes = 1 MB of T)
#define NSR   7                      // ceil(50000 / 8192)
#define PNB   256                    // partition blocks
#define PNT   256                    // partition threads/block
#define PTOT  (PNB * PNT)            // 65536 threads, strided edge walk

typedef __attribute__((ext_vector_type(8))) _Float16 half8;
typedef __attribute__((ext_vector_type(4))) float f32x4;

// ---- gather+accumulate macro body (lane<12 only), unroll-16 / 4 / scalar ----
#define PROP_GATHER_LOOP(TSRC)                                                  \
    {                                                                           \
        int e16 = s + ((e - s) & ~15);                                          \
        for (; p < e16; p += 16) {                                              \
            float ww[16]; uint2 hv[16];                                         \
            _Pragma("unroll")                                                   \
            for (int j = 0; j < 16; ++j) {                                      \
                uint2 er = edges[p + j];                                        \
                ww[j] = __uint_as_float(er.y);                                  \
                hv[j] = *reinterpret_cast<const uint2*>(                        \
                    TSRC + (size_t)er.x * TPAD + 4 * lane);                     \
            }                                                                   \
            _Pragma("unroll")                                                   \
            for (int j = 0; j < 16; ++j) {                                      \
                __half2 h01 = *reinterpret_cast<__half2*>(&hv[j].x);            \
                __half2 h23 = *reinterpret_cast<__half2*>(&hv[j].y);            \
                a0 += ww[j] * __low2float(h01);                                 \
                a1 += ww[j] * __high2float(h01);                                \
                a2 += ww[j] * __low2float(h23);                                 \
                a3 += ww[j] * __high2float(h23);                                \
            }                                                                   \
        }                                                                       \
        int e4b = p + ((e - p) & ~3);                                           \
        for (; p < e4b; p += 4) {                                               \
            float ww[4]; uint2 hv[4];                                           \
            _Pragma("unroll")                                                   \
            for (int j = 0; j < 4; ++j) {                                       \
                uint2 er = edges[p + j];                                        \
                ww[j] = __uint_as_float(er.y);                                  \
                hv[j] = *reinterpret_cast<const uint2*>(                        \
                    TSRC + (size_t)er.x * TPAD + 4 * lane);                     \
            }                                                                   \
            _Pragma("unroll")                                                   \
            for (int j = 0; j < 4; ++j) {                                       \
                __half2 h01 = *reinterpret_cast<__half2*>(&hv[j].x);            \
                __half2 h23 = *reinterpret_cast<__half2*>(&hv[j].y);            \
                a0 += ww[j] * __low2float(h01);                                 \
                a1 += ww[j] * __high2float(h01);                                \
                a2 += ww[j] * __low2float(h23);                                 \
                a3 += ww[j] * __high2float(h23);                                \
            }                                                                   \
        }                                                                       \
        for (; p < e; ++p) {                                                    \
            uint2 er = edges[p];                                                \
            float wv = __uint_as_float(er.y);                                   \
            uint2 hv = *reinterpret_cast<const uint2*>(                         \
                TSRC + (size_t)er.x * TPAD + 4 * lane);                         \
            __half2 h01 = *reinterpret_cast<__half2*>(&hv.x);                   \
            __half2 h23 = *reinterpret_cast<__half2*>(&hv.y);                   \
            a0 += wv * __low2float(h01);                                        \
            a1 += wv * __high2float(h01);                                       \
            a2 += wv * __low2float(h23);                                        \
            a3 += wv * __high2float(h23);                                       \
        }                                                                       \
    }

// ---- P1: per-block bucket counts (deterministic sums) ----
__global__ __launch_bounds__(PNT) void part_count_kernel(
    const int* __restrict__ row, int* __restrict__ bsum7)
{
    __shared__ int cnt[NSR];
    int t = threadIdx.x;
    if (t < NSR) cnt[t] = 0;
    __syncthreads();
    int tid = blockIdx.x * PNT + t;
    int c0 = 0, c1 = 0, c2 = 0, c3 = 0, c4 = 0, c5 = 0, c6 = 0;
    for (int i = tid; i < N_EDGES; i += PTOT) {
        int b = row[i] >> SRSH;
        c0 += (b == 0); c1 += (b == 1); c2 += (b == 2); c3 += (b == 3);
        c4 += (b == 4); c5 += (b == 5); c6 += (b == 6);
    }
    if (c0) atomicAdd(&cnt[0], c0);
    if (c1) atomicAdd(&cnt[1], c1);
    if (c2) atomicAdd(&cnt[2], c2);
    if (c3) atomicAdd(&cnt[3], c3);
    if (c4) atomicAdd(&cnt[4], c4);
    if (c5) atomicAdd(&cnt[5], c5);
    if (c6) atomicAdd(&cnt[6], c6);
    __syncthreads();
    if (t < NSR) bsum7[blockIdx.x * NSR + t] = cnt[t];
}

// ---- P2: blockoff[blk][b] = bucketBase[b] + prefix of block sums ----
__global__ __launch_bounds__(256) void part_scan_kernel(int* __restrict__ bsum7)
{
    __shared__ int ws[NSR][4];
    __shared__ int tot[NSR];
    int t = threadIdx.x;
    int lane = t & 63, wid = t >> 6;
    int myc[NSR], mypre[NSR];
#pragma unroll
    for (int b = 0; b < NSR; ++b) myc[b] = bsum7[t * NSR + b];
#pragma unroll
    for (int b = 0; b < NSR; ++b) {
        int v = myc[b];
        for (int d = 1; d < 64; d <<= 1) {
            int u = __shfl_up(v, d);
            if (lane >= d) v += u;
        }
        if (lane == 63) ws[b][wid] = v;
        mypre[b] = v - myc[b];
    }
    __syncthreads();
    if (t == 0) {
#pragma unroll
        for (int b = 0; b < NSR; ++b) {
            int run = 0;
            for (int i = 0; i < 4; ++i) { int x = ws[b][i]; ws[b][i] = run; run += x; }
            tot[b] = run;
        }
        int run = 0;
#pragma unroll
        for (int b = 0; b < NSR; ++b) { int x = tot[b]; tot[b] = run; run += x; }
    }
    __syncthreads();
#pragma unroll
    for (int b = 0; b < NSR; ++b)
        bsum7[t * NSR + b] = tot[b] + ws[b][wid] + mypre[b];
}

// ---- P3: stable scatter into source-range-partitioned arrays ----
__global__ __launch_bounds__(PNT) void part_scatter_kernel(
    const int* __restrict__ row, const int* __restrict__ col,
    const float* __restrict__ w, const int* __restrict__ blockoff,
    int* __restrict__ row2, int* __restrict__ col2, float* __restrict__ w2)
{
    __shared__ int ws[NSR][4];
    int t = threadIdx.x;
    int tid = blockIdx.x * PNT + t;
    int lane = t & 63, wid = t >> 6;
    // recount (registers)
    int c0 = 0, c1 = 0, c2 = 0, c3 = 0, c4 = 0, c5 = 0, c6 = 0;
    for (int i = tid; i < N_EDGES; i += PTOT) {
        int b = row[i] >> SRSH;
        c0 += (b == 0); c1 += (b == 1); c2 += (b == 2); c3 += (b == 3);
        c4 += (b == 4); c5 += (b == 5); c6 += (b == 6);
    }
    int cArr[NSR] = {c0, c1, c2, c3, c4, c5, c6};
    int pre[NSR];
#pragma unroll
    for (int b = 0; b < NSR; ++b) {
        int v = cArr[b];
        for (int d = 1; d < 64; d <<= 1) {
            int u = __shfl_up(v, d);
            if (lane >= d) v += u;
        }
        if (lane == 63) ws[b][wid] = v;
        pre[b] = v - cArr[b];
    }
    __syncthreads();
    if (t == 0) {
#pragma unroll
        for (int b = 0; b < NSR; ++b) {
            int run = 0;
            for (int i = 0; i < 4; ++i) { int x = ws[b][i]; ws[b][i] = run; run += x; }
        }
    }
    __syncthreads();
    int pos0 = blockoff[blockIdx.x * NSR + 0] + ws[0][wid] + pre[0];
    int pos1 = blockoff[blockIdx.x * NSR + 1] + ws[1][wid] + pre[1];
    int pos2 = blockoff[blockIdx.x * NSR + 2] + ws[2][wid] + pre[2];
    int pos3 = blockoff[blockIdx.x * NSR + 3] + ws[3][wid] + pre[3];
    int pos4 = blockoff[blockIdx.x * NSR + 4] + ws[4][wid] + pre[4];
    int pos5 = blockoff[blockIdx.x * NSR + 5] + ws[5][wid] + pre[5];
    int pos6 = blockoff[blockIdx.x * NSR + 6] + ws[6][wid] + pre[6];
    for (int i = tid; i < N_EDGES; i += PTOT) {
        int r = row[i];
        int cl = col[i];
        float wv = w[i];
        int b = r >> SRSH;
        int p;
        if      (b == 0) p = pos0++;
        else if (b == 1) p = pos1++;
        else if (b == 2) p = pos2++;
        else if (b == 3) p = pos3++;
        else if (b == 4) p = pos4++;
        else if (b == 5) p = pos5++;
        else             p = pos6++;
        row2[p] = r; col2[p] = cl; w2[p] = wv;
    }
}

// ---- pass A: partitioned LDS histogram (cnt by col packed u16, deg by row f32) ----
__global__ __launch_bounds__(HTHREADS) void hist_part_kernel(
    const int* __restrict__ row, const int* __restrict__ col,
    const float* __restrict__ w,
    unsigned short* __restrict__ pc, float* __restrict__ pd)
{
    __shared__ unsigned lc32[RANGE / 2];  // 12.5 KB
    __shared__ float    ld[RANGE];        // 25 KB
    int t = threadIdx.x;
    for (int i = t; i < RANGE / 2; i += HTHREADS) lc32[i] = 0u;
    for (int i = t; i < RANGE; i += HTHREADS) ld[i] = 0.f;
    __syncthreads();
    int r = blockIdx.x / BPR;        // node range
    int b = blockIdx.x % BPR;        // edge slice
    int base = r * RANGE;
    int lo = b * SLICE;
    for (int e0 = lo + t * 4; e0 < lo + SLICE; e0 += HTHREADS * 4) {
        int4   c4 = *(const int4*)&col[e0];
        int4   r4 = *(const int4*)&row[e0];
        float4 w4 = *(const float4*)&w[e0];
        int ci, ri;
        ci = c4.x - base; if ((unsigned)ci < RANGE) atomicAdd(&lc32[ci >> 1], 1u << ((ci & 1) * 16));
        ri = r4.x - base; if ((unsigned)ri < RANGE) atomicAdd(&ld[ri], w4.x);
        ci = c4.y - base; if ((unsigned)ci < RANGE) atomicAdd(&lc32[ci >> 1], 1u << ((ci & 1) * 16));
        ri = r4.y - base; if ((unsigned)ri < RANGE) atomicAdd(&ld[ri], w4.y);
        ci = c4.z - base; if ((unsigned)ci < RANGE) atomicAdd(&lc32[ci >> 1], 1u << ((ci & 1) * 16));
        ri = r4.z - base; if ((unsigned)ri < RANGE) atomicAdd(&ld[ri], w4.z);
        ci = c4.w - base; if ((unsigned)ci < RANGE) atomicAdd(&lc32[ci >> 1], 1u << ((ci & 1) * 16));
        ri = r4.w - base; if ((unsigned)ri < RANGE) atomicAdd(&ld[ri], w4.w);
    }
    __syncthreads();
    unsigned short* pcb = pc + (size_t)blockIdx.x * RANGE;
    float*          pdb = pd + (size_t)blockIdx.x * RANGE;
    for (int i = t; i < RANGE; i += HTHREADS) {
        pcb[i] = (unsigned short)((lc32[i >> 1] >> ((i & 1) * 16)) & 0xFFFFu);
        pdb[i] = ld[i];
    }
}

// ---- fold partials: dinv, per-slice prefix (pc in place), intra-block scan ----
__global__ __launch_bounds__(256) void reduce_kernel(
    unsigned short* __restrict__ pc, const float* __restrict__ pd,
    float* __restrict__ dinv, int* __restrict__ off, int* __restrict__ bsum)
{
    int t = threadIdx.x;
    int n = blockIdx.x * 256 + t;
    int c = 0; float d = 0.f;
    if (n < N_NODES) {
        int r = n / RANGE, i = n - r * RANGE;
        size_t base = (size_t)r * BPR * RANGE + i;
        unsigned csum = 0;
        for (int b = 0; b < BPR; ++b) {
            size_t idx = base + (size_t)b * RANGE;
            unsigned x = pc[idx];
            pc[idx] = (unsigned short)csum;
            csum += x;
            d += pd[idx];
        }
        c = (int)csum;
        dinv[n] = d > 0.f ? rsqrtf(d) : 0.f;
    }
    int lane = t & 63, wid = t >> 6;
    int v = c;
    for (int s = 1; s < 64; s <<= 1) {
        int u = __shfl_up(v, s);
        if (lane >= s) v += u;
    }
    __shared__ int ws[4];
    if (lane == 63) ws[wid] = v;
    __syncthreads();
    int wb = 0;
    for (int i = 0; i < 4; ++i) if (i < wid) wb += ws[i];
    int ex = (v - c) + wb;
    if (n < N_NODES) off[n] = ex;
    if (t == 255) bsum[blockIdx.x] = ex + c;
}

// ---- exclusive scan of 196 block sums ----
__global__ __launch_bounds__(256) void bsum_scan_kernel(
    int* __restrict__ bsum, int* __restrict__ off)
{
    int t = threadIdx.x;
    int orig = (t < NBLK) ? bsum[t] : 0;
    int lane = t & 63, wid = t >> 6;
    int v = orig;
    for (int s = 1; s < 64; s <<= 1) {
        int u = __shfl_up(v, s);
        if (lane >= s) v += u;
    }
    __shared__ int ws[4];
    if (lane == 63) ws[wid] = v;
    __syncthreads();
    int wb = 0;
    for (int i = 0; i < 4; ++i) if (i < wid) wb += ws[i];
    int ex = (v - orig) + wb;
    if (t < NBLK) bsum[t] = ex;
    if (t == NBLK - 1) off[N_NODES] = ex + orig;
}

// ---- add block prefix back ----
__global__ __launch_bounds__(256) void add_off_kernel(
    int* __restrict__ off, const int* __restrict__ bsum)
{
    int n = blockIdx.x * 256 + threadIdx.x;
    if (n < N_NODES) off[n] += bsum[n >> 8];
}

// ---- pass D: scatter via re-derived LDS ranks — zero global atomics ----
__global__ __launch_bounds__(HTHREADS) void scatter_part_kernel(
    const int* __restrict__ row, const int* __restrict__ col,
    const float* __restrict__ w, const float* __restrict__ dinv,
    const int* __restrict__ off, const unsigned short* __restrict__ pc,
    uint2* __restrict__ edges)
{
    __shared__ unsigned lc32[RANGE / 2];  // 12.5 KB
    int t = threadIdx.x;
    for (int i = t; i < RANGE / 2; i += HTHREADS) lc32[i] = 0u;
    __syncthreads();
    int r = blockIdx.x / BPR;
    int b = blockIdx.x % BPR;
    int base = r * RANGE;
    int lo = b * SLICE;
    const unsigned short* pcb = pc + (size_t)blockIdx.x * RANGE;
    for (int e0 = lo + t * 4; e0 < lo + SLICE; e0 += HTHREADS * 4) {
        int4   c4 = *(const int4*)&col[e0];
        int4   r4 = *(const int4*)&row[e0];
        float4 w4 = *(const float4*)&w[e0];
        #pragma unroll
        for (int j = 0; j < 4; ++j) {
            int c  = (j == 0) ? c4.x : (j == 1) ? c4.y : (j == 2) ? c4.z : c4.w;
            int rw = (j == 0) ? r4.x : (j == 1) ? r4.y : (j == 2) ? r4.z : r4.w;
            float we = (j == 0) ? w4.x : (j == 1) ? w4.y : (j == 2) ? w4.z : w4.w;
            int ci = c - base;
            if ((unsigned)ci < RANGE) {
                unsigned old = atomicAdd(&lc32[ci >> 1], 1u << ((ci & 1) * 16));
                unsigned lrank = (old >> ((ci & 1) * 16)) & 0xFFFFu;
                float nr = -dinv[rw] * we * dinv[c];
                int pos = off[c] + (int)pcb[ci] + (int)lrank;
                edges[pos] = make_uint2((unsigned)rw, __float_as_uint(nr));
            }
        }
    }
}

// ---- MFMA xf: xf = relu(x @ W_in + b_in), one wave per 16-node tile ----
__global__ __launch_bounds__(256) void xf_mfma_kernel(
    const float* __restrict__ x, const float* __restrict__ Win,
    const float* __restrict__ bin, float* __restrict__ xf_out,
    __half* __restrict__ T0h)
{
    __shared__ half8 Wf[3][4][64];   // 12288 B
    __shared__ float bs[EMB];
    int t = threadIdx.x;
    for (int idx = t; idx < 3 * 4 * 64; idx += 256) {
        int j = idx >> 8;
        int rem = idx & 255;
        int s = rem >> 6;
        int l = rem & 63;
        int colw = j * 16 + (l & 15);
        int k0 = s * 32 + (l >> 4) * 8;
        half8 v;
        #pragma unroll
        for (int i = 0; i < 8; ++i)
            v[i] = (_Float16)Win[(k0 + i) * EMB + colw];
        Wf[j][s][l] = v;
    }
    if (t < EMB) bs[t] = bin[t];
    __syncthreads();

    int wid = t >> 6, lane = t & 63;
    int nt = blockIdx.x * 4 + wid;
    if (nt >= NTILES) return;
    int n0 = nt * 16;
    int arow = lane & 15, kg = lane >> 4;

    const float* xr = x + (size_t)(n0 + arow) * F_IN + kg * 8;
    half8 a[4];
    #pragma unroll
    for (int s = 0; s < 4; ++s) {
        f32x4 lo = *reinterpret_cast<const f32x4*>(xr + s * 32);
        f32x4 hi = *reinterpret_cast<const f32x4*>(xr + s * 32 + 4);
        half8 av;
        av[0] = (_Float16)lo[0]; av[1] = (_Float16)lo[1];
        av[2] = (_Float16)lo[2]; av[3] = (_Float16)lo[3];
        av[4] = (_Float16)hi[0]; av[5] = (_Float16)hi[1];
        av[6] = (_Float16)hi[2]; av[7] = (_Float16)hi[3];
        a[s] = av;
    }

    f32x4 c0 = {0.f, 0.f, 0.f, 0.f}, c1 = c0, c2 = c0;
    #pragma unroll
    for (int s = 0; s < 4; ++s) {
        c0 = __builtin_amdgcn_mfma_f32_16x16x32_f16(a[s], Wf[0][s][lane], c0, 0, 0, 0);
        c1 = __builtin_amdgcn_mfma_f32_16x16x32_f16(a[s], Wf[1][s][lane], c1, 0, 0, 0);
        c2 = __builtin_amdgcn_mfma_f32_16x16x32_f16(a[s], Wf[2][s][lane], c2, 0, 0, 0);
    }

    int ccol = lane & 15;
    #pragma unroll
    for (int j = 0; j < 3; ++j) {
        int colg = j * 16 + ccol;
        float bias = bs[colg];
        f32x4 cj = (j == 0) ? c0 : (j == 1) ? c1 : c2;
        #pragma unroll
        for (int r = 0; r < 4; ++r) {
            int n = n0 + kg * 4 + r;
            float v = fmaxf(cj[r] + bias, 0.f);
            xf_out[(size_t)n * EMB + colg] = v;
            T0h[(size_t)n * TPAD + colg] = __float2half_rn(v);
        }
    }
    {
        int n = n0 + (lane >> 2);
        int cp = 48 + (lane & 3) * 4;
        *reinterpret_cast<uint2*>(T0h + (size_t)n * TPAD + cp) = make_uint2(0u, 0u);
    }
}

// ---- k=1 prop: T1 = prop(T0); out_acc = T0@W0 + T1@W1 (pure write) ----
__global__ __launch_bounds__(256) void prop_k1_kernel(
    const int* __restrict__ off, const uint2* __restrict__ edges,
    const __half* __restrict__ T0, __half* __restrict__ T1,
    const float* __restrict__ W0, const float* __restrict__ W1,
    float* __restrict__ out_acc)
{
    __shared__ float W0s[EMB * HID];
    __shared__ float W1s[EMB * HID];
    __shared__ float tdS[16][EMB + 1];
    __shared__ float t0S[16][EMB + 1];
    int t = threadIdx.x;
    for (int i = t; i < EMB * HID; i += 256) { W0s[i] = W0[i]; W1s[i] = W1[i]; }
    __syncthreads();   // covers weight staging only

    int grp = t >> 4, lane = t & 15;
    int g = blockIdx.x * 16 + grp;

    float a0 = 0.f, a1 = 0.f, a2 = 0.f, a3 = 0.f;
    if (lane < 12) {
        int s = off[g], e = off[g + 1];
        int p = s;
        PROP_GATHER_LOOP(T0)
        uint2 tv = *reinterpret_cast<const uint2*>(T0 + (size_t)g * TPAD + 4 * lane);
        __half2 t01 = *reinterpret_cast<__half2*>(&tv.x);
        __half2 t23 = *reinterpret_cast<__half2*>(&tv.y);
        t0S[grp][4 * lane]     = __low2float(t01);
        t0S[grp][4 * lane + 1] = __high2float(t01);
        t0S[grp][4 * lane + 2] = __low2float(t23);
        t0S[grp][4 * lane + 3] = __high2float(t23);
        tdS[grp][4 * lane]     = a0;
        tdS[grp][4 * lane + 1] = a1;
        tdS[grp][4 * lane + 2] = a2;
        tdS[grp][4 * lane + 3] = a3;
    }
    {
        __half2 h01, h23;
        h01.x = __float2half_rn(a0); h01.y = __float2half_rn(a1);
        h23.x = __float2half_rn(a2); h23.y = __float2half_rn(a3);
        uint2 ov;
        ov.x = *reinterpret_cast<unsigned*>(&h01);
        ov.y = *reinterpret_cast<unsigned*>(&h23);
        *reinterpret_cast<uint2*>(T1 + (size_t)g * TPAD + 4 * lane) = ov;
    }
    // tdS/t0S rows are wave-local — no barrier needed

    float o0 = 0.f, o1 = 0.f, o2 = 0.f;
#pragma unroll 8
    for (int c = 0; c < EMB; ++c) {
        float t1v = tdS[grp][c];
        float t0v = t0S[grp][c];
        o0 += t1v * W1s[c * HID + lane]      + t0v * W0s[c * HID + lane];
        o1 += t1v * W1s[c * HID + lane + 16] + t0v * W0s[c * HID + lane + 16];
        o2 += t1v * W1s[c * HID + lane + 32] + t0v * W0s[c * HID + lane + 32];
    }
    float* orow = out_acc + (size_t)g * HID;
    orow[lane]      = o0;
    orow[lane + 16] = o1;
    orow[lane + 32] = o2;
}

// ---- k=2..5: T_k = 2*prop(T_{k-1}) - T_{k-2}; out_acc += T_k @ W_k ----
__global__ __launch_bounds__(256) void prop_fused_kernel(
    const int* __restrict__ off, const uint2* __restrict__ edges,
    const __half* __restrict__ tsrc, const __half* __restrict__ tprev,
    __half* __restrict__ tdst, const float* __restrict__ Wk,
    float* __restrict__ out_acc)
{
    __shared__ float Ws[EMB * HID];
    __shared__ float tdS[16][EMB + 1];
    int t = threadIdx.x;
    for (int i = t; i < EMB * HID; i += 256) Ws[i] = Wk[i];
    __syncthreads();   // covers weight staging only

    int grp = t >> 4, lane = t & 15;
    int g = blockIdx.x * 16 + grp;

    float a0 = 0.f, a1 = 0.f, a2 = 0.f, a3 = 0.f;
    if (lane < 12) {
        int s = off[g], e = off[g + 1];
        int p = s;
        PROP_GATHER_LOOP(tsrc)
        uint2 tv = *reinterpret_cast<const uint2*>(tprev + (size_t)g * TPAD + 4 * lane);
        __half2 t01 = *reinterpret_cast<__half2*>(&tv.x);
        __half2 t23 = *reinterpret_cast<__half2*>(&tv.y);
        a0 = 2.f * a0 - __low2float(t01);
        a1 = 2.f * a1 - __high2float(t01);
        a2 = 2.f * a2 - __low2float(t23);
        a3 = 2.f * a3 - __high2float(t23);
        tdS[grp][4 * lane]     = a0;
        tdS[grp][4 * lane + 1] = a1;
        tdS[grp][4 * lane + 2] = a2;
        tdS[grp][4 * lane + 3] = a3;
    }
    {
        __half2 h01, h23;
        h01.x = __float2half_rn(a0); h01.y = __float2half_rn(a1);
        h23.x = __float2half_rn(a2); h23.y = __float2half_rn(a3);
        uint2 ov;
        ov.x = *reinterpret_cast<unsigned*>(&h01);
        ov.y = *reinterpret_cast<unsigned*>(&h23);
        *reinterpret_cast<uint2*>(tdst + (size_t)g * TPAD + 4 * lane) = ov;
    }
    // tdS row is wave-local — no barrier needed

    float o0 = 0.f, o1 = 0.f, o2 = 0.f;
#pragma unroll 8
    for (int c = 0; c < EMB; ++c) {
        float tv = tdS[grp][c];
        o0 += tv * Ws[c * HID + lane];
        o1 += tv * Ws[c * HID + lane + 16];
        o2 += tv * Ws[c * HID + lane + 32];
    }
    float* orow = out_acc + (size_t)g * HID;
    orow[lane]      += o0;
    orow[lane + 16] += o1;
    orow[lane + 32] += o2;
}

// ---- k=6 prop fused with final: y = relu(out_acc + T6@W6 + b_cheb) @ W_out + b_out ----
__global__ __launch_bounds__(256) void prop_final_kernel(
    const int* __restrict__ off, const uint2* __restrict__ edges,
    const __half* __restrict__ tsrc, const __half* __restrict__ tprev,
    const float* __restrict__ Wk, const float* __restrict__ out_acc,
    const float* __restrict__ bch, const float* __restrict__ Wout,
    const float* __restrict__ bout, float* __restrict__ y)
{
    __shared__ float Ws[EMB * HID];
    __shared__ float Wo[HID * OUTF];
    __shared__ float tdS[16][EMB + 1];
    __shared__ float vS[16][HID + 1];
    __shared__ float bchS[HID];
    __shared__ float boS[OUTF];
    int t = threadIdx.x;
    for (int i = t; i < EMB * HID; i += 256) Ws[i] = Wk[i];
    for (int i = t; i < HID * OUTF; i += 256) Wo[i] = Wout[i];
    if (t < HID) bchS[t] = bch[t];
    if (t < OUTF) boS[t] = bout[t];
    __syncthreads();   // covers weight/bias staging only

    int grp = t >> 4, lane = t & 15;
    int g = blockIdx.x * 16 + grp;

    float a0 = 0.f, a1 = 0.f, a2 = 0.f, a3 = 0.f;
    if (lane < 12) {
        int s = off[g], e = off[g + 1];
        int p = s;
        PROP_GATHER_LOOP(tsrc)
        uint2 tv = *reinterpret_cast<const uint2*>(tprev + (size_t)g * TPAD + 4 * lane);
        __half2 t01 = *reinterpret_cast<__half2*>(&tv.x);
        __half2 t23 = *reinterpret_cast<__half2*>(&tv.y);
        a0 = 2.f * a0 - __low2float(t01);
        a1 = 2.f * a1 - __high2float(t01);
        a2 = 2.f * a2 - __low2float(t23);
        a3 = 2.f * a3 - __high2float(t23);
        tdS[grp][4 * lane]     = a0;
        tdS[grp][4 * lane + 1] = a1;
        tdS[grp][4 * lane + 2] = a2;
        tdS[grp][4 * lane + 3] = a3;
    }
    // tdS/vS rows are wave-local — no barrier needed

    float o0 = 0.f, o1 = 0.f, o2 = 0.f;
#pragma unroll 8
    for (int c = 0; c < EMB; ++c) {
        float tv = tdS[grp][c];
        o0 += tv * Ws[c * HID + lane];
        o1 += tv * Ws[c * HID + lane + 16];
        o2 += tv * Ws[c * HID + lane + 32];
    }
    const float* orow = out_acc + (size_t)g * HID;
    vS[grp][lane]      = fmaxf(orow[lane]      + o0 + bchS[lane],      0.f);
    vS[grp][lane + 16] = fmaxf(orow[lane + 16] + o1 + bchS[lane + 16], 0.f);
    vS[grp][lane + 32] = fmaxf(orow[lane + 32] + o2 + bchS[lane + 32], 0.f);

    float y0 = boS[4 * lane], y1 = boS[4 * lane + 1];
    float y2 = boS[4 * lane + 2], y3 = boS[4 * lane + 3];
#pragma unroll 8
    for (int h = 0; h < HID; ++h) {
        float v = vS[grp][h];
        float4 w4 = *reinterpret_cast<const float4*>(&Wo[h * OUTF + 4 * lane]);
        y0 += v * w4.x; y1 += v * w4.y; y2 += v * w4.z; y3 += v * w4.w;
    }
    *reinterpret_cast<float4*>(y + (size_t)g * OUTF + 4 * lane) =
        make_float4(y0, y1, y2, y3);
}

extern "C" void kernel_launch(void* const* d_in, const int* in_sizes, int n_in,
                              void* d_out, int out_size, void* d_ws, size_t ws_size,
                              hipStream_t stream)
{
    const float* x    = (const float*)d_in[0];
    const int*   ei   = (const int*)d_in[1];
    const float* ew   = (const float*)d_in[2];
    const float* Win  = (const float*)d_in[3];
    const float* bin  = (const float*)d_in[4];
    const float* Wch  = (const float*)d_in[5];   // [7,48,48]
    const float* bch  = (const float*)d_in[6];
    const float* Wout = (const float*)d_in[7];
    const float* bout = (const float*)d_in[8];

    const int* row = ei;
    const int* col = ei + N_EDGES;

    float* y_out  = (float*)d_out;                           // [N,64]
    float* xf_out = (float*)d_out + (size_t)N_NODES * OUTF;  // [N,48]

    char* p = (char*)d_ws;
    auto carve = [&](size_t bytes) {
        void* q = p;
        p += (bytes + 255) & ~(size_t)255;
        return q;
    };
    unsigned short* pc = (unsigned short*)carve((size_t)NR * BPR * RANGE * 2); // 6.4 MB
    float*    pd  = (float*)carve((size_t)NR * BPR * RANGE * 4);               // 12.8 MB
    float*    dinv = (float*)carve(N_NODES * 4);
    int*      off  = (int*)  carve((N_NODES + 1) * 4);
    int*      bsum = (int*)  carve(NBLK * 4);
    int*      bsum7 = (int*) carve((size_t)PNB * NSR * 4);
    int*      row2 = (int*)  carve((size_t)N_EDGES * 4);
    int*      col2 = (int*)  carve((size_t)N_EDGES * 4);
    float*    w2   = (float*)carve((size_t)N_EDGES * 4);
    uint2*    edges = (uint2*)carve((size_t)N_EDGES * 8);
    float*    out_acc = (float*)carve((size_t)N_NODES * HID * 4);
    __half*   T0h = (__half*)carve((size_t)N_NODES * TPAD * 2);   // 6.4 MB each
    __half*   TAh = (__half*)carve((size_t)N_NODES * TPAD * 2);
    __half*   TBh = (__half*)carve((size_t)N_NODES * TPAD * 2);
    __half*   TCh = (__half*)carve((size_t)N_NODES * TPAD * 2);

    // source-range partition (deterministic counting sort, 7 buckets)
    part_count_kernel<<<PNB, PNT, 0, stream>>>(row, bsum7);
    part_scan_kernel<<<1, 256, 0, stream>>>(bsum7);
    part_scatter_kernel<<<PNB, PNT, 0, stream>>>(row, col, ew, bsum7, row2, col2, w2);

    // graph preprocessing on partitioned arrays — zero global atomics
    hist_part_kernel<<<NR * BPR, HTHREADS, 0, stream>>>(row2, col2, w2, pc, pd);
    reduce_kernel<<<NBLK, 256, 0, stream>>>(pc, pd, dinv, off, bsum);
    bsum_scan_kernel<<<1, 256, 0, stream>>>(bsum, off);
    add_off_kernel<<<NBLK, 256, 0, stream>>>(off, bsum);
    scatter_part_kernel<<<NR * BPR, HTHREADS, 0, stream>>>(row2, col2, w2, dinv, off, pc, edges);

    // xf via MFMA -> f32 d_out tail + padded fp16 T0
    xf_mfma_kernel<<<(NTILES + 3) / 4, 256, 0, stream>>>(x, Win, bin, xf_out, T0h);

    const int prop_grid = NTILES;   // 3125

    // k=1: T1 = prop(T0); out_acc = T0@W0 + T1@W1 (write)
    prop_k1_kernel<<<prop_grid, 256, 0, stream>>>(off, edges, T0h, TAh,
                                                  Wch, Wch + EMB * HID, out_acc);
    // k=2..5 with fused GEMM — proven 3-buffer rotation.
    const __half* A = T0h;  // T_{k-2}
    __half*       B = TAh;  // T_{k-1}
    __half* bufs[3] = {TBh, TCh, TAh};
    for (int k = 2; k < KCH - 1; ++k) {
        __half* C = bufs[(k - 2) % 3];
        prop_fused_kernel<<<prop_grid, 256, 0, stream>>>(off, edges, B, A,
                                                         C, Wch + (size_t)k * EMB * HID, out_acc);
        A = B; B = C;
    }
    // k=6: fused prop + final
    prop_final_kernel<<<prop_grid, 256, 0, stream>>>(off, edges, B, A,
                                                     Wch + (size_t)(KCH - 1) * EMB * HID,
                                                     out_acc, bch, Wout, bout, y_out);
}

// Round 17
// 373.872 us; speedup vs baseline: 1.1556x; 1.1556x over previous
//
#include <hip/hip_runtime.h>
#include <hip/hip_fp16.h>

#define N_NODES 50000
#define N_EDGES 1600000
#define F_IN    128
#define EMB     48
#define HID     48
#define OUTF    64
#define KCH     7
#define TPAD    64                   // padded T row length (halves) = 128 B

#define NR    8                      // node ranges (LDS partitions)
#define RANGE (N_NODES / NR)         // 6250 counters
#define BPR   64                     // edge slices
#define SLICE (N_EDGES / BPR)        // 25000 edges per slice (div by 4)
#define HTHREADS 512
#define NBLK  ((N_NODES + 255) / 256)   // 196 reduce blocks
#define NTILES (N_NODES / 16)        // 3125 node tiles

typedef __attribute__((ext_vector_type(8))) _Float16 half8;
typedef __attribute__((ext_vector_type(4))) float f32x4;

// ---- paired-16B gather: lanes 0-5 -> even edge, 6-11 -> odd edge.
// Each lane accumulates 8 features (a[0..7] f32) at offset 8*sub.
#define PROP_GATHER_PAIRED(TSRC)                                                \
    {                                                                           \
        int e16 = s + ((e - s) & ~15);                                          \
        for (; p < e16; p += 16) {                                              \
            float ww[8]; uint4 hv[8];                                           \
            _Pragma("unroll")                                                   \
            for (int m = 0; m < 8; ++m) {                                       \
                uint2 er = edges[p + 2 * m + which];                            \
                ww[m] = __uint_as_float(er.y);                                  \
                hv[m] = *reinterpret_cast<const uint4*>(                        \
                    TSRC + (size_t)er.x * TPAD + 8 * sub);                      \
            }                                                                   \
            _Pragma("unroll")                                                   \
            for (int m = 0; m < 8; ++m) {                                       \
                __half2 h01 = *reinterpret_cast<__half2*>(&hv[m].x);            \
                __half2 h23 = *reinterpret_cast<__half2*>(&hv[m].y);            \
                __half2 h45 = *reinterpret_cast<__half2*>(&hv[m].z);            \
                __half2 h67 = *reinterpret_cast<__half2*>(&hv[m].w);            \
                a[0] += ww[m] * __low2float(h01);                               \
                a[1] += ww[m] * __high2float(h01);                              \
                a[2] += ww[m] * __low2float(h23);                               \
                a[3] += ww[m] * __high2float(h23);                              \
                a[4] += ww[m] * __low2float(h45);                               \
                a[5] += ww[m] * __high2float(h45);                              \
                a[6] += ww[m] * __low2float(h67);                               \
                a[7] += ww[m] * __high2float(h67);                              \
            }                                                                   \
        }                                                                       \
        int e2 = p + ((e - p) & ~1);                                            \
        for (; p < e2; p += 2) {                                                \
            uint2 er = edges[p + which];                                        \
            float wv = __uint_as_float(er.y);                                   \
            uint4 hv = *reinterpret_cast<const uint4*>(                         \
                TSRC + (size_t)er.x * TPAD + 8 * sub);                          \
            __half2 h01 = *reinterpret_cast<__half2*>(&hv.x);                   \
            __half2 h23 = *reinterpret_cast<__half2*>(&hv.y);                   \
            __half2 h45 = *reinterpret_cast<__half2*>(&hv.z);                   \
            __half2 h67 = *reinterpret_cast<__half2*>(&hv.w);                   \
            a[0] += wv * __low2float(h01);  a[1] += wv * __high2float(h01);     \
            a[2] += wv * __low2float(h23);  a[3] += wv * __high2float(h23);     \
            a[4] += wv * __low2float(h45);  a[5] += wv * __high2float(h45);     \
            a[6] += wv * __low2float(h67);  a[7] += wv * __high2float(h67);     \
        }                                                                       \
        if (p < e && which == 0) {                                              \
            uint2 er = edges[p];                                                \
            float wv = __uint_as_float(er.y);                                   \
            uint4 hv = *reinterpret_cast<const uint4*>(                         \
                TSRC + (size_t)er.x * TPAD + 8 * sub);                          \
            __half2 h01 = *reinterpret_cast<__half2*>(&hv.x);                   \
            __half2 h23 = *reinterpret_cast<__half2*>(&hv.y);                   \
            __half2 h45 = *reinterpret_cast<__half2*>(&hv.z);                   \
            __half2 h67 = *reinterpret_cast<__half2*>(&hv.w);                   \
            a[0] += wv * __low2float(h01);  a[1] += wv * __high2float(h01);     \
            a[2] += wv * __low2float(h23);  a[3] += wv * __high2float(h23);     \
            a[4] += wv * __low2float(h45);  a[5] += wv * __high2float(h45);     \
            a[6] += wv * __low2float(h67);  a[7] += wv * __high2float(h67);     \
        }                                                                       \
    }

// combine even/odd partials into tdS[grp] (same-wave ordered phases)
#define PROP_COMBINE()                                                          \
    if (lane < 6) {                                                             \
        _Pragma("unroll")                                                       \
        for (int i = 0; i < 8; ++i) tdS[grp][8 * sub + i] = a[i];               \
    }                                                                           \
    if (lane >= 6 && lane < 12) {                                               \
        _Pragma("unroll")                                                       \
        for (int i = 0; i < 8; ++i) tdS[grp][8 * sub + i] += a[i];              \
    }

// ---- pass A: partitioned LDS histogram (cnt by col packed u16, deg by row f32) ----
__global__ __launch_bounds__(HTHREADS) void hist_part_kernel(
    const int* __restrict__ row, const int* __restrict__ col,
    const float* __restrict__ w,
    unsigned short* __restrict__ pc, float* __restrict__ pd)
{
    __shared__ unsigned lc32[RANGE / 2];  // 12.5 KB
    __shared__ float    ld[RANGE];        // 25 KB
    int t = threadIdx.x;
    for (int i = t; i < RANGE / 2; i += HTHREADS) lc32[i] = 0u;
    for (int i = t; i < RANGE; i += HTHREADS) ld[i] = 0.f;
    __syncthreads();
    int r = blockIdx.x / BPR;        // node range
    int b = blockIdx.x % BPR;        // edge slice
    int base = r * RANGE;
    int lo = b * SLICE;
    for (int e0 = lo + t * 4; e0 < lo + SLICE; e0 += HTHREADS * 4) {
        int4   c4 = *(const int4*)&col[e0];
        int4   r4 = *(const int4*)&row[e0];
        float4 w4 = *(const float4*)&w[e0];
        int ci, ri;
        ci = c4.x - base; if ((unsigned)ci < RANGE) atomicAdd(&lc32[ci >> 1], 1u << ((ci & 1) * 16));
        ri = r4.x - base; if ((unsigned)ri < RANGE) atomicAdd(&ld[ri], w4.x);
        ci = c4.y - base; if ((unsigned)ci < RANGE) atomicAdd(&lc32[ci >> 1], 1u << ((ci & 1) * 16));
        ri = r4.y - base; if ((unsigned)ri < RANGE) atomicAdd(&ld[ri], w4.y);
        ci = c4.z - base; if ((unsigned)ci < RANGE) atomicAdd(&lc32[ci >> 1], 1u << ((ci & 1) * 16));
        ri = r4.z - base; if ((unsigned)ri < RANGE) atomicAdd(&ld[ri], w4.z);
        ci = c4.w - base; if ((unsigned)ci < RANGE) atomicAdd(&lc32[ci >> 1], 1u << ((ci & 1) * 16));
        ri = r4.w - base; if ((unsigned)ri < RANGE) atomicAdd(&ld[ri], w4.w);
    }
    __syncthreads();
    unsigned short* pcb = pc + (size_t)blockIdx.x * RANGE;
    float*          pdb = pd + (size_t)blockIdx.x * RANGE;
    for (int i = t; i < RANGE; i += HTHREADS) {
        pcb[i] = (unsigned short)((lc32[i >> 1] >> ((i & 1) * 16)) & 0xFFFFu);
        pdb[i] = ld[i];
    }
}

// ---- fold partials: dinv, per-slice prefix (pc in place), intra-block scan ----
__global__ __launch_bounds__(256) void reduce_kernel(
    unsigned short* __restrict__ pc, const float* __restrict__ pd,
    float* __restrict__ dinv, int* __restrict__ off, int* __restrict__ bsum)
{
    int t = threadIdx.x;
    int n = blockIdx.x * 256 + t;
    int c = 0; float d = 0.f;
    if (n < N_NODES) {
        int r = n / RANGE, i = n - r * RANGE;
        size_t base = (size_t)r * BPR * RANGE + i;
        unsigned csum = 0;
        for (int b = 0; b < BPR; ++b) {
            size_t idx = base + (size_t)b * RANGE;
            unsigned x = pc[idx];
            pc[idx] = (unsigned short)csum;
            csum += x;
            d += pd[idx];
        }
        c = (int)csum;
        dinv[n] = d > 0.f ? rsqrtf(d) : 0.f;
    }
    int lane = t & 63, wid = t >> 6;
    int v = c;
    for (int s = 1; s < 64; s <<= 1) {
        int u = __shfl_up(v, s);
        if (lane >= s) v += u;
    }
    __shared__ int ws[4];
    if (lane == 63) ws[wid] = v;
    __syncthreads();
    int wb = 0;
    for (int i = 0; i < 4; ++i) if (i < wid) wb += ws[i];
    int ex = (v - c) + wb;
    if (n < N_NODES) off[n] = ex;
    if (t == 255) bsum[blockIdx.x] = ex + c;
}

// ---- exclusive scan of 196 block sums ----
__global__ __launch_bounds__(256) void bsum_scan_kernel(
    int* __restrict__ bsum, int* __restrict__ off)
{
    int t = threadIdx.x;
    int orig = (t < NBLK) ? bsum[t] : 0;
    int lane = t & 63, wid = t >> 6;
    int v = orig;
    for (int s = 1; s < 64; s <<= 1) {
        int u = __shfl_up(v, s);
        if (lane >= s) v += u;
    }
    __shared__ int ws[4];
    if (lane == 63) ws[wid] = v;
    __syncthreads();
    int wb = 0;
    for (int i = 0; i < 4; ++i) if (i < wid) wb += ws[i];
    int ex = (v - orig) + wb;
    if (t < NBLK) bsum[t] = ex;
    if (t == NBLK - 1) off[N_NODES] = ex + orig;
}

// ---- add block prefix back ----
__global__ __launch_bounds__(256) void add_off_kernel(
    int* __restrict__ off, const int* __restrict__ bsum)
{
    int n = blockIdx.x * 256 + threadIdx.x;
    if (n < N_NODES) off[n] += bsum[n >> 8];
}

// ---- pass D: scatter via re-derived LDS ranks — zero global atomics ----
__global__ __launch_bounds__(HTHREADS) void scatter_part_kernel(
    const int* __restrict__ row, const int* __restrict__ col,
    const float* __restrict__ w, const float* __restrict__ dinv,
    const int* __restrict__ off, const unsigned short* __restrict__ pc,
    uint2* __restrict__ edges)
{
    __shared__ unsigned lc32[RANGE / 2];  // 12.5 KB
    int t = threadIdx.x;
    for (int i = t; i < RANGE / 2; i += HTHREADS) lc32[i] = 0u;
    __syncthreads();
    int r = blockIdx.x / BPR;
    int b = blockIdx.x % BPR;
    int base = r * RANGE;
    int lo = b * SLICE;
    const unsigned short* pcb = pc + (size_t)blockIdx.x * RANGE;
    for (int e0 = lo + t * 4; e0 < lo + SLICE; e0 += HTHREADS * 4) {
        int4   c4 = *(const int4*)&col[e0];
        int4   r4 = *(const int4*)&row[e0];
        float4 w4 = *(const float4*)&w[e0];
        #pragma unroll
        for (int j = 0; j < 4; ++j) {
            int c  = (j == 0) ? c4.x : (j == 1) ? c4.y : (j == 2) ? c4.z : c4.w;
            int rw = (j == 0) ? r4.x : (j == 1) ? r4.y : (j == 2) ? r4.z : r4.w;
            float we = (j == 0) ? w4.x : (j == 1) ? w4.y : (j == 2) ? w4.z : w4.w;
            int ci = c - base;
            if ((unsigned)ci < RANGE) {
                unsigned old = atomicAdd(&lc32[ci >> 1], 1u << ((ci & 1) * 16));
                unsigned lrank = (old >> ((ci & 1) * 16)) & 0xFFFFu;
                float nr = -dinv[rw] * we * dinv[c];
                int pos = off[c] + (int)pcb[ci] + (int)lrank;
                edges[pos] = make_uint2((unsigned)rw, __float_as_uint(nr));
            }
        }
    }
}

// ---- MFMA xf: xf = relu(x @ W_in + b_in), one wave per 16-node tile ----
__global__ __launch_bounds__(256) void xf_mfma_kernel(
    const float* __restrict__ x, const float* __restrict__ Win,
    const float* __restrict__ bin, float* __restrict__ xf_out,
    __half* __restrict__ T0h)
{
    __shared__ half8 Wf[3][4][64];   // 12288 B
    __shared__ float bs[EMB];
    int t = threadIdx.x;
    for (int idx = t; idx < 3 * 4 * 64; idx += 256) {
        int j = idx >> 8;
        int rem = idx & 255;
        int s = rem >> 6;
        int l = rem & 63;
        int colw = j * 16 + (l & 15);
        int k0 = s * 32 + (l >> 4) * 8;
        half8 v;
        #pragma unroll
        for (int i = 0; i < 8; ++i)
            v[i] = (_Float16)Win[(k0 + i) * EMB + colw];
        Wf[j][s][l] = v;
    }
    if (t < EMB) bs[t] = bin[t];
    __syncthreads();

    int wid = t >> 6, lane = t & 63;
    int nt = blockIdx.x * 4 + wid;
    if (nt >= NTILES) return;
    int n0 = nt * 16;
    int arow = lane & 15, kg = lane >> 4;

    const float* xr = x + (size_t)(n0 + arow) * F_IN + kg * 8;
    half8 a[4];
    #pragma unroll
    for (int s = 0; s < 4; ++s) {
        f32x4 lo = *reinterpret_cast<const f32x4*>(xr + s * 32);
        f32x4 hi = *reinterpret_cast<const f32x4*>(xr + s * 32 + 4);
        half8 av;
        av[0] = (_Float16)lo[0]; av[1] = (_Float16)lo[1];
        av[2] = (_Float16)lo[2]; av[3] = (_Float16)lo[3];
        av[4] = (_Float16)hi[0]; av[5] = (_Float16)hi[1];
        av[6] = (_Float16)hi[2]; av[7] = (_Float16)hi[3];
        a[s] = av;
    }

    f32x4 c0 = {0.f, 0.f, 0.f, 0.f}, c1 = c0, c2 = c0;
    #pragma unroll
    for (int s = 0; s < 4; ++s) {
        c0 = __builtin_amdgcn_mfma_f32_16x16x32_f16(a[s], Wf[0][s][lane], c0, 0, 0, 0);
        c1 = __builtin_amdgcn_mfma_f32_16x16x32_f16(a[s], Wf[1][s][lane], c1, 0, 0, 0);
        c2 = __builtin_amdgcn_mfma_f32_16x16x32_f16(a[s], Wf[2][s][lane], c2, 0, 0, 0);
    }

    int ccol = lane & 15;
    #pragma unroll
    for (int j = 0; j < 3; ++j) {
        int colg = j * 16 + ccol;
        float bias = bs[colg];
        f32x4 cj = (j == 0) ? c0 : (j == 1) ? c1 : c2;
        #pragma unroll
        for (int r = 0; r < 4; ++r) {
            int n = n0 + kg * 4 + r;
            float v = fmaxf(cj[r] + bias, 0.f);
            xf_out[(size_t)n * EMB + colg] = v;
            T0h[(size_t)n * TPAD + colg] = __float2half_rn(v);
        }
    }
    {
        int n = n0 + (lane >> 2);
        int cp = 48 + (lane & 3) * 4;
        *reinterpret_cast<uint2*>(T0h + (size_t)n * TPAD + cp) = make_uint2(0u, 0u);
    }
}

// ---- k=1 prop: T1 = prop(T0); out_acc = T0@W0 + T1@W1 (pure write) ----
__global__ __launch_bounds__(256) void prop_k1_kernel(
    const int* __restrict__ off, const uint2* __restrict__ edges,
    const __half* __restrict__ T0, __half* __restrict__ T1,
    const float* __restrict__ W0, const float* __restrict__ W1,
    float* __restrict__ out_acc)
{
    __shared__ float W0s[EMB * HID];
    __shared__ float W1s[EMB * HID];
    __shared__ float tdS[16][EMB + 1];
    __shared__ float t0S[16][EMB + 1];
    int t = threadIdx.x;
    for (int i = t; i < EMB * HID; i += 256) { W0s[i] = W0[i]; W1s[i] = W1[i]; }
    __syncthreads();   // covers weight staging only

    int grp = t >> 4, lane = t & 15;
    int g = blockIdx.x * 16 + grp;
    int sub = (lane < 6) ? lane : lane - 6;
    int which = (lane < 6) ? 0 : 1;

    float a[8] = {0.f, 0.f, 0.f, 0.f, 0.f, 0.f, 0.f, 0.f};
    if (lane < 12) {
        int s = off[g], e = off[g + 1];
        int p = s;
        PROP_GATHER_PAIRED(T0)
    }
    PROP_COMBINE()

    // T1 write + stage own T0 row; read final sums from tdS
    if (lane < 12) {
        float s0 = tdS[grp][4 * lane];
        float s1 = tdS[grp][4 * lane + 1];
        float s2 = tdS[grp][4 * lane + 2];
        float s3 = tdS[grp][4 * lane + 3];
        __half2 h01, h23;
        h01.x = __float2half_rn(s0); h01.y = __float2half_rn(s1);
        h23.x = __float2half_rn(s2); h23.y = __float2half_rn(s3);
        uint2 ov;
        ov.x = *reinterpret_cast<unsigned*>(&h01);
        ov.y = *reinterpret_cast<unsigned*>(&h23);
        *reinterpret_cast<uint2*>(T1 + (size_t)g * TPAD + 4 * lane) = ov;
        uint2 tv = *reinterpret_cast<const uint2*>(T0 + (size_t)g * TPAD + 4 * lane);
        __half2 t01 = *reinterpret_cast<__half2*>(&tv.x);
        __half2 t23 = *reinterpret_cast<__half2*>(&tv.y);
        t0S[grp][4 * lane]     = __low2float(t01);
        t0S[grp][4 * lane + 1] = __high2float(t01);
        t0S[grp][4 * lane + 2] = __low2float(t23);
        t0S[grp][4 * lane + 3] = __high2float(t23);
    } else {
        // keep padded T1 region zero
        *reinterpret_cast<uint2*>(T1 + (size_t)g * TPAD + 4 * lane) = make_uint2(0u, 0u);
    }
    // tdS/t0S rows wave-local — no barrier needed

    float o0 = 0.f, o1 = 0.f, o2 = 0.f;
#pragma unroll 8
    for (int c = 0; c < EMB; ++c) {
        float t1v = tdS[grp][c];
        float t0v = t0S[grp][c];
        o0 += t1v * W1s[c * HID + lane]      + t0v * W0s[c * HID + lane];
        o1 += t1v * W1s[c * HID + lane + 16] + t0v * W0s[c * HID + lane + 16];
        o2 += t1v * W1s[c * HID + lane + 32] + t0v * W0s[c * HID + lane + 32];
    }
    float* orow = out_acc + (size_t)g * HID;
    orow[lane]      = o0;
    orow[lane + 16] = o1;
    orow[lane + 32] = o2;
}

// ---- k=2..5: T_k = 2*prop(T_{k-1}) - T_{k-2}; out_acc += T_k @ W_k ----
__global__ __launch_bounds__(256) void prop_fused_kernel(
    const int* __restrict__ off, const uint2* __restrict__ edges,
    const __half* __restrict__ tsrc, const __half* __restrict__ tprev,
    __half* __restrict__ tdst, const float* __restrict__ Wk,
    float* __restrict__ out_acc)
{
    __shared__ float Ws[EMB * HID];
    __shared__ float tdS[16][EMB + 1];
    int t = threadIdx.x;
    for (int i = t; i < EMB * HID; i += 256) Ws[i] = Wk[i];
    __syncthreads();   // covers weight staging only

    int grp = t >> 4, lane = t & 15;
    int g = blockIdx.x * 16 + grp;
    int sub = (lane < 6) ? lane : lane - 6;
    int which = (lane < 6) ? 0 : 1;

    float a[8] = {0.f, 0.f, 0.f, 0.f, 0.f, 0.f, 0.f, 0.f};
    if (lane < 12) {
        int s = off[g], e = off[g + 1];
        int p = s;
        PROP_GATHER_PAIRED(tsrc)
    }
    PROP_COMBINE()

    if (lane < 12) {
        float s0 = tdS[grp][4 * lane];
        float s1 = tdS[grp][4 * lane + 1];
        float s2 = tdS[grp][4 * lane + 2];
        float s3 = tdS[grp][4 * lane + 3];
        uint2 tv = *reinterpret_cast<const uint2*>(tprev + (size_t)g * TPAD + 4 * lane);
        __half2 t01 = *reinterpret_cast<__half2*>(&tv.x);
        __half2 t23 = *reinterpret_cast<__half2*>(&tv.y);
        s0 = 2.f * s0 - __low2float(t01);
        s1 = 2.f * s1 - __high2float(t01);
        s2 = 2.f * s2 - __low2float(t23);
        s3 = 2.f * s3 - __high2float(t23);
        tdS[grp][4 * lane]     = s0;
        tdS[grp][4 * lane + 1] = s1;
        tdS[grp][4 * lane + 2] = s2;
        tdS[grp][4 * lane + 3] = s3;
        __half2 h01, h23;
        h01.x = __float2half_rn(s0); h01.y = __float2half_rn(s1);
        h23.x = __float2half_rn(s2); h23.y = __float2half_rn(s3);
        uint2 ov;
        ov.x = *reinterpret_cast<unsigned*>(&h01);
        ov.y = *reinterpret_cast<unsigned*>(&h23);
        *reinterpret_cast<uint2*>(tdst + (size_t)g * TPAD + 4 * lane) = ov;
    } else {
        *reinterpret_cast<uint2*>(tdst + (size_t)g * TPAD + 4 * lane) = make_uint2(0u, 0u);
    }
    // tdS row wave-local — no barrier needed

    float o0 = 0.f, o1 = 0.f, o2 = 0.f;
#pragma unroll 8
    for (int c = 0; c < EMB; ++c) {
        float tv = tdS[grp][c];
        o0 += tv * Ws[c * HID + lane];
        o1 += tv * Ws[c * HID + lane + 16];
        o2 += tv * Ws[c * HID + lane + 32];
    }
    float* orow = out_acc + (size_t)g * HID;
    orow[lane]      += o0;
    orow[lane + 16] += o1;
    orow[lane + 32] += o2;
}

// ---- k=6 prop fused with final: y = relu(out_acc + T6@W6 + b_cheb) @ W_out + b_out ----
__global__ __launch_bounds__(256) void prop_final_kernel(
    const int* __restrict__ off, const uint2* __restrict__ edges,
    const __half* __restrict__ tsrc, const __half* __restrict__ tprev,
    const float* __restrict__ Wk, const float* __restrict__ out_acc,
    const float* __restrict__ bch, const float* __restrict__ Wout,
    const float* __restrict__ bout, float* __restrict__ y)
{
    __shared__ float Ws[EMB * HID];
    __shared__ float Wo[HID * OUTF];
    __shared__ float tdS[16][EMB + 1];
    __shared__ float vS[16][HID + 1];
    __shared__ float bchS[HID];
    __shared__ float boS[OUTF];
    int t = threadIdx.x;
    for (int i = t; i < EMB * HID; i += 256) Ws[i] = Wk[i];
    for (int i = t; i < HID * OUTF; i += 256) Wo[i] = Wout[i];
    if (t < HID) bchS[t] = bch[t];
    if (t < OUTF) boS[t] = bout[t];
    __syncthreads();   // covers weight/bias staging only

    int grp = t >> 4, lane = t & 15;
    int g = blockIdx.x * 16 + grp;
    int sub = (lane < 6) ? lane : lane - 6;
    int which = (lane < 6) ? 0 : 1;

    float a[8] = {0.f, 0.f, 0.f, 0.f, 0.f, 0.f, 0.f, 0.f};
    if (lane < 12) {
        int s = off[g], e = off[g + 1];
        int p = s;
        PROP_GATHER_PAIRED(tsrc)
    }
    PROP_COMBINE()

    if (lane < 12) {
        float s0 = tdS[grp][4 * lane];
        float s1 = tdS[grp][4 * lane + 1];
        float s2 = tdS[grp][4 * lane + 2];
        float s3 = tdS[grp][4 * lane + 3];
        uint2 tv = *reinterpret_cast<const uint2*>(tprev + (size_t)g * TPAD + 4 * lane);
        __half2 t01 = *reinterpret_cast<__half2*>(&tv.x);
        __half2 t23 = *reinterpret_cast<__half2*>(&tv.y);
        tdS[grp][4 * lane]     = 2.f * s0 - __low2float(t01);
        tdS[grp][4 * lane + 1] = 2.f * s1 - __high2float(t01);
        tdS[grp][4 * lane + 2] = 2.f * s2 - __low2float(t23);
        tdS[grp][4 * lane + 3] = 2.f * s3 - __high2float(t23);
    }
    // tdS/vS rows wave-local — no barrier needed

    float o0 = 0.f, o1 = 0.f, o2 = 0.f;
#pragma unroll 8
    for (int c = 0; c < EMB; ++c) {
        float tv = tdS[grp][c];
        o0 += tv * Ws[c * HID + lane];
        o1 += tv * Ws[c * HID + lane + 16];
        o2 += tv * Ws[c * HID + lane + 32];
    }
    const float* orow = out_acc + (size_t)g * HID;
    vS[grp][lane]      = fmaxf(orow[lane]      + o0 + bchS[lane],      0.f);
    vS[grp][lane + 16] = fmaxf(orow[lane + 16] + o1 + bchS[lane + 16], 0.f);
    vS[grp][lane + 32] = fmaxf(orow[lane + 32] + o2 + bchS[lane + 32], 0.f);

    float y0 = boS[4 * lane], y1 = boS[4 * lane + 1];
    float y2 = boS[4 * lane + 2], y3 = boS[4 * lane + 3];
#pragma unroll 8
    for (int h = 0; h < HID; ++h) {
        float v = vS[grp][h];
        float4 w4 = *reinterpret_cast<const float4*>(&Wo[h * OUTF + 4 * lane]);
        y0 += v * w4.x; y1 += v * w4.y; y2 += v * w4.z; y3 += v * w4.w;
    }
    *reinterpret_cast<float4*>(y + (size_t)g * OUTF + 4 * lane) =
        make_float4(y0, y1, y2, y3);
}

extern "C" void kernel_launch(void* const* d_in, const int* in_sizes, int n_in,
                              void* d_out, int out_size, void* d_ws, size_t ws_size,
                              hipStream_t stream)
{
    const float* x    = (const float*)d_in[0];
    const int*   ei   = (const int*)d_in[1];
    const float* ew   = (const float*)d_in[2];
    const float* Win  = (const float*)d_in[3];
    const float* bin  = (const float*)d_in[4];
    const float* Wch  = (const float*)d_in[5];   // [7,48,48]
    const float* bch  = (const float*)d_in[6];
    const float* Wout = (const float*)d_in[7];
    const float* bout = (const float*)d_in[8];

    const int* row = ei;
    const int* col = ei + N_EDGES;

    float* y_out  = (float*)d_out;                           // [N,64]
    float* xf_out = (float*)d_out + (size_t)N_NODES * OUTF;  // [N,48]

    char* p = (char*)d_ws;
    auto carve = [&](size_t bytes) {
        void* q = p;
        p += (bytes + 255) & ~(size_t)255;
        return q;
    };
    unsigned short* pc = (unsigned short*)carve((size_t)NR * BPR * RANGE * 2); // 6.4 MB
    float*    pd  = (float*)carve((size_t)NR * BPR * RANGE * 4);               // 12.8 MB
    float*    dinv = (float*)carve(N_NODES * 4);
    int*      off  = (int*)  carve((N_NODES + 1) * 4);
    int*      bsum = (int*)  carve(NBLK * 4);
    uint2*    edges = (uint2*)carve((size_t)N_EDGES * 8);
    float*    out_acc = (float*)carve((size_t)N_NODES * HID * 4);
    __half*   T0h = (__half*)carve((size_t)N_NODES * TPAD * 2);   // 6.4 MB each
    __half*   TAh = (__half*)carve((size_t)N_NODES * TPAD * 2);
    __half*   TBh = (__half*)carve((size_t)N_NODES * TPAD * 2);
    __half*   TCh = (__half*)carve((size_t)N_NODES * TPAD * 2);

    // graph preprocessing — zero global atomics, hierarchical scan
    hist_part_kernel<<<NR * BPR, HTHREADS, 0, stream>>>(row, col, ew, pc, pd);
    reduce_kernel<<<NBLK, 256, 0, stream>>>(pc, pd, dinv, off, bsum);
    bsum_scan_kernel<<<1, 256, 0, stream>>>(bsum, off);
    add_off_kernel<<<NBLK, 256, 0, stream>>>(off, bsum);
    scatter_part_kernel<<<NR * BPR, HTHREADS, 0, stream>>>(row, col, ew, dinv, off, pc, edges);

    // xf via MFMA -> f32 d_out tail + padded fp16 T0
    xf_mfma_kernel<<<(NTILES + 3) / 4, 256, 0, stream>>>(x, Win, bin, xf_out, T0h);

    const int prop_grid = NTILES;   // 3125

    // k=1: T1 = prop(T0); out_acc = T0@W0 + T1@W1 (write)
    prop_k1_kernel<<<prop_grid, 256, 0, stream>>>(off, edges, T0h, TAh,
                                                  Wch, Wch + EMB * HID, out_acc);
    // k=2..5 with fused GEMM — proven 3-buffer rotation.
    const __half* A = T0h;  // T_{k-2}
    __half*       B = TAh;  // T_{k-1}
    __half* bufs[3] = {TBh, TCh, TAh};
    for (int k = 2; k < KCH - 1; ++k) {
        __half* C = bufs[(k - 2) % 3];
        prop_fused_kernel<<<prop_grid, 256, 0, stream>>>(off, edges, B, A,
                                                         C, Wch + (size_t)k * EMB * HID, out_acc);
        A = B; B = C;
    }
    // k=6: fused prop + final
    prop_final_kernel<<<prop_grid, 256, 0, stream>>>(off, edges, B, A,
                                                     Wch + (size_t)(KCH - 1) * EMB * HID,
                                                     out_acc, bch, Wout, bout, y_out);
}

// Round 18
// 340.381 us; speedup vs baseline: 1.2693x; 1.0984x over previous
//
#include <hip/hip_runtime.h>
#include <hip/hip_fp16.h>

#define N_NODES 50000
#define N_EDGES 1600000
#define F_IN    128
#define EMB     48
#define HID     48
#define OUTF    64
#define KCH     7
#define TPAD    64                   // padded T row length (halves) = 128 B

#define NR    8                      // node ranges (LDS partitions)
#define RANGE (N_NODES / NR)         // 6250 counters
#define BPR   64                     // edge slices
#define SLICE (N_EDGES / BPR)        // 25000 edges per slice (div by 4)
#define HTHREADS 512
#define NBLK  ((N_NODES + 255) / 256)   // 196 reduce blocks
#define NTILES (N_NODES / 16)        // 3125 node tiles

typedef __attribute__((ext_vector_type(8))) _Float16 half8;
typedef __attribute__((ext_vector_type(4))) float f32x4;

// ---- gather+accumulate (lane<12 only), unroll-16 / 4 / scalar (round-15 form) ----
#define PROP_GATHER_LOOP(TSRC)                                                  \
    {                                                                           \
        int e16 = s + ((e - s) & ~15);                                          \
        for (; p < e16; p += 16) {                                              \
            float ww[16]; uint2 hv[16];                                         \
            _Pragma("unroll")                                                   \
            for (int j = 0; j < 16; ++j) {                                      \
                uint2 er = edges[p + j];                                        \
                ww[j] = __uint_as_float(er.y);                                  \
                hv[j] = *reinterpret_cast<const uint2*>(                        \
                    TSRC + (size_t)er.x * TPAD + 4 * lane);                     \
            }                                                                   \
            _Pragma("unroll")                                                   \
            for (int j = 0; j < 16; ++j) {                                      \
                __half2 h01 = *reinterpret_cast<__half2*>(&hv[j].x);            \
                __half2 h23 = *reinterpret_cast<__half2*>(&hv[j].y);            \
                a0 += ww[j] * __low2float(h01);                                 \
                a1 += ww[j] * __high2float(h01);                                \
                a2 += ww[j] * __low2float(h23);                                 \
                a3 += ww[j] * __high2float(h23);                                \
            }                                                                   \
        }                                                                       \
        int e4b = p + ((e - p) & ~3);                                           \
        for (; p < e4b; p += 4) {                                               \
            float ww[4]; uint2 hv[4];                                           \
            _Pragma("unroll")                                                   \
            for (int j = 0; j < 4; ++j) {                                       \
                uint2 er = edges[p + j];                                        \
                ww[j] = __uint_as_float(er.y);                                  \
                hv[j] = *reinterpret_cast<const uint2*>(                        \
                    TSRC + (size_t)er.x * TPAD + 4 * lane);                     \
            }                                                                   \
            _Pragma("unroll")                                                   \
            for (int j = 0; j < 4; ++j) {                                       \
                __half2 h01 = *reinterpret_cast<__half2*>(&hv[j].x);            \
                __half2 h23 = *reinterpret_cast<__half2*>(&hv[j].y);            \
                a0 += ww[j] * __low2float(h01);                                 \
                a1 += ww[j] * __high2float(h01);                                \
                a2 += ww[j] * __low2float(h23);                                 \
                a3 += ww[j] * __high2float(h23);                                \
            }                                                                   \
        }                                                                       \
        for (; p < e; ++p) {                                                    \
            uint2 er = edges[p];                                                \
            float wv = __uint_as_float(er.y);                                   \
            uint2 hv = *reinterpret_cast<const uint2*>(                         \
                TSRC + (size_t)er.x * TPAD + 4 * lane);                         \
            __half2 h01 = *reinterpret_cast<__half2*>(&hv.x);                   \
            __half2 h23 = *reinterpret_cast<__half2*>(&hv.y);                   \
            a0 += wv * __low2float(h01);                                        \
            a1 += wv * __high2float(h01);                                       \
            a2 += wv * __low2float(h23);                                        \
            a3 += wv * __high2float(h23);                                       \
        }                                                                       \
    }

// ---- pass A: partitioned LDS histogram; ALSO records per-edge rank (u16) ----
__global__ __launch_bounds__(HTHREADS) void hist_part_kernel(
    const int* __restrict__ row, const int* __restrict__ col,
    const float* __restrict__ w,
    unsigned short* __restrict__ pc, float* __restrict__ pd,
    unsigned short* __restrict__ rank16)
{
    __shared__ unsigned lc32[RANGE / 2];  // 12.5 KB
    __shared__ float    ld[RANGE];        // 25 KB
    int t = threadIdx.x;
    for (int i = t; i < RANGE / 2; i += HTHREADS) lc32[i] = 0u;
    for (int i = t; i < RANGE; i += HTHREADS) ld[i] = 0.f;
    __syncthreads();
    int r = blockIdx.x / BPR;        // node range
    int b = blockIdx.x % BPR;        // edge slice
    int base = r * RANGE;
    int lo = b * SLICE;
    for (int e0 = lo + t * 4; e0 < lo + SLICE; e0 += HTHREADS * 4) {
        int4   c4 = *(const int4*)&col[e0];
        int4   r4 = *(const int4*)&row[e0];
        float4 w4 = *(const float4*)&w[e0];
        #pragma unroll
        for (int j = 0; j < 4; ++j) {
            int c  = (j == 0) ? c4.x : (j == 1) ? c4.y : (j == 2) ? c4.z : c4.w;
            int rw = (j == 0) ? r4.x : (j == 1) ? r4.y : (j == 2) ? r4.z : r4.w;
            float we = (j == 0) ? w4.x : (j == 1) ? w4.y : (j == 2) ? w4.z : w4.w;
            int ci = c - base;
            if ((unsigned)ci < RANGE) {
                unsigned sh = (ci & 1) * 16;
                unsigned old = atomicAdd(&lc32[ci >> 1], 1u << sh);
                rank16[e0 + j] = (unsigned short)((old >> sh) & 0xFFFFu);
            }
            int ri = rw - base;
            if ((unsigned)ri < RANGE) atomicAdd(&ld[ri], we);
        }
    }
    __syncthreads();
    unsigned short* pcb = pc + (size_t)blockIdx.x * RANGE;
    float*          pdb = pd + (size_t)blockIdx.x * RANGE;
    for (int i = t; i < RANGE; i += HTHREADS) {
        pcb[i] = (unsigned short)((lc32[i >> 1] >> ((i & 1) * 16)) & 0xFFFFu);
        pdb[i] = ld[i];
    }
}

// ---- fold partials: dinv, per-slice prefix (pc in place), intra-block scan ----
__global__ __launch_bounds__(256) void reduce_kernel(
    unsigned short* __restrict__ pc, const float* __restrict__ pd,
    float* __restrict__ dinv, int* __restrict__ off, int* __restrict__ bsum)
{
    int t = threadIdx.x;
    int n = blockIdx.x * 256 + t;
    int c = 0; float d = 0.f;
    if (n < N_NODES) {
        int r = n / RANGE, i = n - r * RANGE;
        size_t base = (size_t)r * BPR * RANGE + i;
        unsigned csum = 0;
        for (int b = 0; b < BPR; ++b) {
            size_t idx = base + (size_t)b * RANGE;
            unsigned x = pc[idx];
            pc[idx] = (unsigned short)csum;
            csum += x;
            d += pd[idx];
        }
        c = (int)csum;
        dinv[n] = d > 0.f ? rsqrtf(d) : 0.f;
    }
    int lane = t & 63, wid = t >> 6;
    int v = c;
    for (int s = 1; s < 64; s <<= 1) {
        int u = __shfl_up(v, s);
        if (lane >= s) v += u;
    }
    __shared__ int ws[4];
    if (lane == 63) ws[wid] = v;
    __syncthreads();
    int wb = 0;
    for (int i = 0; i < 4; ++i) if (i < wid) wb += ws[i];
    int ex = (v - c) + wb;
    if (n < N_NODES) off[n] = ex;
    if (t == 255) bsum[blockIdx.x] = ex + c;
}

// ---- exclusive scan of 196 block sums ----
__global__ __launch_bounds__(256) void bsum_scan_kernel(
    int* __restrict__ bsum, int* __restrict__ off)
{
    int t = threadIdx.x;
    int orig = (t < NBLK) ? bsum[t] : 0;
    int lane = t & 63, wid = t >> 6;
    int v = orig;
    for (int s = 1; s < 64; s <<= 1) {
        int u = __shfl_up(v, s);
        if (lane >= s) v += u;
    }
    __shared__ int ws[4];
    if (lane == 63) ws[wid] = v;
    __syncthreads();
    int wb = 0;
    for (int i = 0; i < 4; ++i) if (i < wid) wb += ws[i];
    int ex = (v - orig) + wb;
    if (t < NBLK) bsum[t] = ex;
    if (t == NBLK - 1) off[N_NODES] = ex + orig;
}

// ---- add block prefix back ----
__global__ __launch_bounds__(256) void add_off_kernel(
    int* __restrict__ off, const int* __restrict__ bsum)
{
    int n = blockIdx.x * 256 + threadIdx.x;
    if (n < N_NODES) off[n] += bsum[n >> 8];
}

// ---- flat scatter: ONE pass over edges using saved rank16 — no re-count ----
__global__ __launch_bounds__(256) void scatter_flat_kernel(
    const int* __restrict__ row, const int* __restrict__ col,
    const float* __restrict__ w, const float* __restrict__ dinv,
    const int* __restrict__ off, const unsigned short* __restrict__ pc,
    const unsigned short* __restrict__ rank16, uint2* __restrict__ edges)
{
    int tid = blockIdx.x * 256 + threadIdx.x;
    int e0 = tid * 4;
    if (e0 >= N_EDGES) return;
    int b = e0 / SLICE;              // slice (constant across the 4-pack)
    int4   c4 = *(const int4*)&col[e0];
    int4   r4 = *(const int4*)&row[e0];
    float4 w4 = *(const float4*)&w[e0];
    ushort4 k4 = *(const ushort4*)&rank16[e0];
    #pragma unroll
    for (int j = 0; j < 4; ++j) {
        int c  = (j == 0) ? c4.x : (j == 1) ? c4.y : (j == 2) ? c4.z : c4.w;
        int rw = (j == 0) ? r4.x : (j == 1) ? r4.y : (j == 2) ? r4.z : r4.w;
        float we = (j == 0) ? w4.x : (j == 1) ? w4.y : (j == 2) ? w4.z : w4.w;
        int rk = (j == 0) ? k4.x : (j == 1) ? k4.y : (j == 2) ? k4.z : k4.w;
        int rg = c / RANGE;
        int clocal = c - rg * RANGE;
        int pre = pc[(size_t)(rg * BPR + b) * RANGE + clocal];
        float nr = -dinv[rw] * we * dinv[c];
        int pos = off[c] + pre + rk;
        edges[pos] = make_uint2((unsigned)rw, __float_as_uint(nr));
    }
}

// ---- MFMA xf: xf = relu(x @ W_in + b_in), one wave per 16-node tile ----
__global__ __launch_bounds__(256) void xf_mfma_kernel(
    const float* __restrict__ x, const float* __restrict__ Win,
    const float* __restrict__ bin, float* __restrict__ xf_out,
    __half* __restrict__ T0h)
{
    __shared__ half8 Wf[3][4][64];   // 12288 B
    __shared__ float bs[EMB];
    int t = threadIdx.x;
    for (int idx = t; idx < 3 * 4 * 64; idx += 256) {
        int j = idx >> 8;
        int rem = idx & 255;
        int s = rem >> 6;
        int l = rem & 63;
        int colw = j * 16 + (l & 15);
        int k0 = s * 32 + (l >> 4) * 8;
        half8 v;
        #pragma unroll
        for (int i = 0; i < 8; ++i)
            v[i] = (_Float16)Win[(k0 + i) * EMB + colw];
        Wf[j][s][l] = v;
    }
    if (t < EMB) bs[t] = bin[t];
    __syncthreads();

    int wid = t >> 6, lane = t & 63;
    int nt = blockIdx.x * 4 + wid;
    if (nt >= NTILES) return;
    int n0 = nt * 16;
    int arow = lane & 15, kg = lane >> 4;

    const float* xr = x + (size_t)(n0 + arow) * F_IN + kg * 8;
    half8 a[4];
    #pragma unroll
    for (int s = 0; s < 4; ++s) {
        f32x4 lo = *reinterpret_cast<const f32x4*>(xr + s * 32);
        f32x4 hi = *reinterpret_cast<const f32x4*>(xr + s * 32 + 4);
        half8 av;
        av[0] = (_Float16)lo[0]; av[1] = (_Float16)lo[1];
        av[2] = (_Float16)lo[2]; av[3] = (_Float16)lo[3];
        av[4] = (_Float16)hi[0]; av[5] = (_Float16)hi[1];
        av[6] = (_Float16)hi[2]; av[7] = (_Float16)hi[3];
        a[s] = av;
    }

    f32x4 c0 = {0.f, 0.f, 0.f, 0.f}, c1 = c0, c2 = c0;
    #pragma unroll
    for (int s = 0; s < 4; ++s) {
        c0 = __builtin_amdgcn_mfma_f32_16x16x32_f16(a[s], Wf[0][s][lane], c0, 0, 0, 0);
        c1 = __builtin_amdgcn_mfma_f32_16x16x32_f16(a[s], Wf[1][s][lane], c1, 0, 0, 0);
        c2 = __builtin_amdgcn_mfma_f32_16x16x32_f16(a[s], Wf[2][s][lane], c2, 0, 0, 0);
    }

    int ccol = lane & 15;
    #pragma unroll
    for (int j = 0; j < 3; ++j) {
        int colg = j * 16 + ccol;
        float bias = bs[colg];
        f32x4 cj = (j == 0) ? c0 : (j == 1) ? c1 : c2;
        #pragma unroll
        for (int r = 0; r < 4; ++r) {
            int n = n0 + kg * 4 + r;
            float v = fmaxf(cj[r] + bias, 0.f);
            xf_out[(size_t)n * EMB + colg] = v;
            T0h[(size_t)n * TPAD + colg] = __float2half_rn(v);
        }
    }
    {
        int n = n0 + (lane >> 2);
        int cp = 48 + (lane & 3) * 4;
        *reinterpret_cast<uint2*>(T0h + (size_t)n * TPAD + cp) = make_uint2(0u, 0u);
    }
}

// ---- k=1 prop: T1 = prop(T0); out_acc = T0@W0 + T1@W1 (pure write) ----
__global__ __launch_bounds__(256) void prop_k1_kernel(
    const int* __restrict__ off, const uint2* __restrict__ edges,
    const __half* __restrict__ T0, __half* __restrict__ T1,
    const float* __restrict__ W0, const float* __restrict__ W1,
    float* __restrict__ out_acc)
{
    __shared__ float W0s[EMB * HID];
    __shared__ float W1s[EMB * HID];
    __shared__ float tdS[16][EMB + 1];
    __shared__ float t0S[16][EMB + 1];
    int t = threadIdx.x;
    for (int i = t; i < EMB * HID; i += 256) { W0s[i] = W0[i]; W1s[i] = W1[i]; }
    __syncthreads();   // covers weight staging only

    int grp = t >> 4, lane = t & 15;
    int g = blockIdx.x * 16 + grp;

    float a0 = 0.f, a1 = 0.f, a2 = 0.f, a3 = 0.f;
    if (lane < 12) {
        int s = off[g], e = off[g + 1];
        int p = s;
        PROP_GATHER_LOOP(T0)
        uint2 tv = *reinterpret_cast<const uint2*>(T0 + (size_t)g * TPAD + 4 * lane);
        __half2 t01 = *reinterpret_cast<__half2*>(&tv.x);
        __half2 t23 = *reinterpret_cast<__half2*>(&tv.y);
        t0S[grp][4 * lane]     = __low2float(t01);
        t0S[grp][4 * lane + 1] = __high2float(t01);
        t0S[grp][4 * lane + 2] = __low2float(t23);
        t0S[grp][4 * lane + 3] = __high2float(t23);
        tdS[grp][4 * lane]     = a0;
        tdS[grp][4 * lane + 1] = a1;
        tdS[grp][4 * lane + 2] = a2;
        tdS[grp][4 * lane + 3] = a3;
    }
    {
        __half2 h01, h23;
        h01.x = __float2half_rn(a0); h01.y = __float2half_rn(a1);
        h23.x = __float2half_rn(a2); h23.y = __float2half_rn(a3);
        uint2 ov;
        ov.x = *reinterpret_cast<unsigned*>(&h01);
        ov.y = *reinterpret_cast<unsigned*>(&h23);
        *reinterpret_cast<uint2*>(T1 + (size_t)g * TPAD + 4 * lane) = ov;
    }
    // tdS/t0S rows are wave-local — no barrier needed

    float o0 = 0.f, o1 = 0.f, o2 = 0.f;
#pragma unroll 8
    for (int c = 0; c < EMB; ++c) {
        float t1v = tdS[grp][c];
        float t0v = t0S[grp][c];
        o0 += t1v * W1s[c * HID + lane]      + t0v * W0s[c * HID + lane];
        o1 += t1v * W1s[c * HID + lane + 16] + t0v * W0s[c * HID + lane + 16];
        o2 += t1v * W1s[c * HID + lane + 32] + t0v * W0s[c * HID + lane + 32];
    }
    float* orow = out_acc + (size_t)g * HID;
    orow[lane]      = o0;
    orow[lane + 16] = o1;
    orow[lane + 32] = o2;
}

// ---- k=2..5: T_k = 2*prop(T_{k-1}) - T_{k-2}; out_acc += T_k @ W_k ----
__global__ __launch_bounds__(256) void prop_fused_kernel(
    const int* __restrict__ off, const uint2* __restrict__ edges,
    const __half* __restrict__ tsrc, const __half* __restrict__ tprev,
    __half* __restrict__ tdst, const float* __restrict__ Wk,
    float* __restrict__ out_acc)
{
    __shared__ float Ws[EMB * HID];
    __shared__ float tdS[16][EMB + 1];
    int t = threadIdx.x;
    for (int i = t; i < EMB * HID; i += 256) Ws[i] = Wk[i];
    __syncthreads();   // covers weight staging only

    int grp = t >> 4, lane = t & 15;
    int g = blockIdx.x * 16 + grp;

    float a0 = 0.f, a1 = 0.f, a2 = 0.f, a3 = 0.f;
    if (lane < 12) {
        int s = off[g], e = off[g + 1];
        int p = s;
        PROP_GATHER_LOOP(tsrc)
        uint2 tv = *reinterpret_cast<const uint2*>(tprev + (size_t)g * TPAD + 4 * lane);
        __half2 t01 = *reinterpret_cast<__half2*>(&tv.x);
        __half2 t23 = *reinterpret_cast<__half2*>(&tv.y);
        a0 = 2.f * a0 - __low2float(t01);
        a1 = 2.f * a1 - __high2float(t01);
        a2 = 2.f * a2 - __low2float(t23);
        a3 = 2.f * a3 - __high2float(t23);
        tdS[grp][4 * lane]     = a0;
        tdS[grp][4 * lane + 1] = a1;
        tdS[grp][4 * lane + 2] = a2;
        tdS[grp][4 * lane + 3] = a3;
    }
    {
        __half2 h01, h23;
        h01.x = __float2half_rn(a0); h01.y = __float2half_rn(a1);
        h23.x = __float2half_rn(a2); h23.y = __float2half_rn(a3);
        uint2 ov;
        ov.x = *reinterpret_cast<unsigned*>(&h01);
        ov.y = *reinterpret_cast<unsigned*>(&h23);
        *reinterpret_cast<uint2*>(tdst + (size_t)g * TPAD + 4 * lane) = ov;
    }
    // tdS row is wave-local — no barrier needed

    float o0 = 0.f, o1 = 0.f, o2 = 0.f;
#pragma unroll 8
    for (int c = 0; c < EMB; ++c) {
        float tv = tdS[grp][c];
        o0 += tv * Ws[c * HID + lane];
        o1 += tv * Ws[c * HID + lane + 16];
        o2 += tv * Ws[c * HID + lane + 32];
    }
    float* orow = out_acc + (size_t)g * HID;
    orow[lane]      += o0;
    orow[lane + 16] += o1;
    orow[lane + 32] += o2;
}

// ---- k=6 prop fused with final: y = relu(out_acc + T6@W6 + b_cheb) @ W_out + b_out ----
__global__ __launch_bounds__(256) void prop_final_kernel(
    const int* __restrict__ off, const uint2* __restrict__ edges,
    const __half* __restrict__ tsrc, const __half* __restrict__ tprev,
    const float* __restrict__ Wk, const float* __restrict__ out_acc,
    const float* __restrict__ bch, const float* __restrict__ Wout,
    const float* __restrict__ bout, float* __restrict__ y)
{
    __shared__ float Ws[EMB * HID];
    __shared__ float Wo[HID * OUTF];
    __shared__ float tdS[16][EMB + 1];
    __shared__ float vS[16][HID + 1];
    __shared__ float bchS[HID];
    __shared__ float boS[OUTF];
    int t = threadIdx.x;
    for (int i = t; i < EMB * HID; i += 256) Ws[i] = Wk[i];
    for (int i = t; i < HID * OUTF; i += 256) Wo[i] = Wout[i];
    if (t < HID) bchS[t] = bch[t];
    if (t < OUTF) boS[t] = bout[t];
    __syncthreads();   // covers weight/bias staging only

    int grp = t >> 4, lane = t & 15;
    int g = blockIdx.x * 16 + grp;

    float a0 = 0.f, a1 = 0.f, a2 = 0.f, a3 = 0.f;
    if (lane < 12) {
        int s = off[g], e = off[g + 1];
        int p = s;
        PROP_GATHER_LOOP(tsrc)
        uint2 tv = *reinterpret_cast<const uint2*>(tprev + (size_t)g * TPAD + 4 * lane);
        __half2 t01 = *reinterpret_cast<__half2*>(&tv.x);
        __half2 t23 = *reinterpret_cast<__half2*>(&tv.y);
        a0 = 2.f * a0 - __low2float(t01);
        a1 = 2.f * a1 - __high2float(t01);
        a2 = 2.f * a2 - __low2float(t23);
        a3 = 2.f * a3 - __high2float(t23);
        tdS[grp][4 * lane]     = a0;
        tdS[grp][4 * lane + 1] = a1;
        tdS[grp][4 * lane + 2] = a2;
        tdS[grp][4 * lane + 3] = a3;
    }
    // tdS/vS rows are wave-local — no barrier needed

    float o0 = 0.f, o1 = 0.f, o2 = 0.f;
#pragma unroll 8
    for (int c = 0; c < EMB; ++c) {
        float tv = tdS[grp][c];
        o0 += tv * Ws[c * HID + lane];
        o1 += tv * Ws[c * HID + lane + 16];
        o2 += tv * Ws[c * HID + lane + 32];
    }
    const float* orow = out_acc + (size_t)g * HID;
    vS[grp][lane]      = fmaxf(orow[lane]      + o0 + bchS[lane],      0.f);
    vS[grp][lane + 16] = fmaxf(orow[lane + 16] + o1 + bchS[lane + 16], 0.f);
    vS[grp][lane + 32] = fmaxf(orow[lane + 32] + o2 + bchS[lane + 32], 0.f);

    float y0 = boS[4 * lane], y1 = boS[4 * lane + 1];
    float y2 = boS[4 * lane + 2], y3 = boS[4 * lane + 3];
#pragma unroll 8
    for (int h = 0; h < HID; ++h) {
        float v = vS[grp][h];
        float4 w4 = *reinterpret_cast<const float4*>(&Wo[h * OUTF + 4 * lane]);
        y0 += v * w4.x; y1 += v * w4.y; y2 += v * w4.z; y3 += v * w4.w;
    }
    *reinterpret_cast<float4*>(y + (size_t)g * OUTF + 4 * lane) =
        make_float4(y0, y1, y2, y3);
}

extern "C" void kernel_launch(void* const* d_in, const int* in_sizes, int n_in,
                              void* d_out, int out_size, void* d_ws, size_t ws_size,
                              hipStream_t stream)
{
    const float* x    = (const float*)d_in[0];
    const int*   ei   = (const int*)d_in[1];
    const float* ew   = (const float*)d_in[2];
    const float* Win  = (const float*)d_in[3];
    const float* bin  = (const float*)d_in[4];
    const float* Wch  = (const float*)d_in[5];   // [7,48,48]
    const float* bch  = (const float*)d_in[6];
    const float* Wout = (const float*)d_in[7];
    const float* bout = (const float*)d_in[8];

    const int* row = ei;
    const int* col = ei + N_EDGES;

    float* y_out  = (float*)d_out;                           // [N,64]
    float* xf_out = (float*)d_out + (size_t)N_NODES * OUTF;  // [N,48]

    char* p = (char*)d_ws;
    auto carve = [&](size_t bytes) {
        void* q = p;
        p += (bytes + 255) & ~(size_t)255;
        return q;
    };
    unsigned short* pc = (unsigned short*)carve((size_t)NR * BPR * RANGE * 2); // 6.4 MB
    float*    pd  = (float*)carve((size_t)NR * BPR * RANGE * 4);               // 12.8 MB
    unsigned short* rank16 = (unsigned short*)carve((size_t)N_EDGES * 2);      // 3.2 MB
    float*    dinv = (float*)carve(N_NODES * 4);
    int*      off  = (int*)  carve((N_NODES + 1) * 4);
    int*      bsum = (int*)  carve(NBLK * 4);
    uint2*    edges = (uint2*)carve((size_t)N_EDGES * 8);
    float*    out_acc = (float*)carve((size_t)N_NODES * HID * 4);
    __half*   T0h = (__half*)carve((size_t)N_NODES * TPAD * 2);   // 6.4 MB each
    __half*   TAh = (__half*)carve((size_t)N_NODES * TPAD * 2);
    __half*   TBh = (__half*)carve((size_t)N_NODES * TPAD * 2);
    __half*   TCh = (__half*)carve((size_t)N_NODES * TPAD * 2);

    // graph preprocessing — zero global atomics, rank saved during hist,
    // single-pass flat scatter
    hist_part_kernel<<<NR * BPR, HTHREADS, 0, stream>>>(row, col, ew, pc, pd, rank16);
    reduce_kernel<<<NBLK, 256, 0, stream>>>(pc, pd, dinv, off, bsum);
    bsum_scan_kernel<<<1, 256, 0, stream>>>(bsum, off);
    add_off_kernel<<<NBLK, 256, 0, stream>>>(off, bsum);
    scatter_flat_kernel<<<(N_EDGES / 4 + 255) / 256, 256, 0, stream>>>(
        row, col, ew, dinv, off, pc, rank16, edges);

    // xf via MFMA -> f32 d_out tail + padded fp16 T0
    xf_mfma_kernel<<<(NTILES + 3) / 4, 256, 0, stream>>>(x, Win, bin, xf_out, T0h);

    const int prop_grid = NTILES;   // 3125

    // k=1: T1 = prop(T0); out_acc = T0@W0 + T1@W1 (write)
    prop_k1_kernel<<<prop_grid, 256, 0, stream>>>(off, edges, T0h, TAh,
                                                  Wch, Wch + EMB * HID, out_acc);
    // k=2..5 with fused GEMM — proven 3-buffer rotation.
    const __half* A = T0h;  // T_{k-2}
    __half*       B = TAh;  // T_{k-1}
    __half* bufs[3] = {TBh, TCh, TAh};
    for (int k = 2; k < KCH - 1; ++k) {
        __half* C = bufs[(k - 2) % 3];
        prop_fused_kernel<<<prop_grid, 256, 0, stream>>>(off, edges, B, A,
                                                         C, Wch + (size_t)k * EMB * HID, out_acc);
        A = B; B = C;
    }
    // k=6: fused prop + final
    prop_final_kernel<<<prop_grid, 256, 0, stream>>>(off, edges, B, A,
                                                     Wch + (size_t)(KCH - 1) * EMB * HID,
                                                     out_acc, bch, Wout, bout, y_out);
}

// Round 19
// 327.454 us; speedup vs baseline: 1.3194x; 1.0395x over previous
//
#include <hip/hip_runtime.h>
#include <hip/hip_fp16.h>

#define N_NODES 50000
#define N_EDGES 1600000
#define F_IN    128
#define EMB     48
#define HID     48
#define OUTF    64
#define KCH     7
#define TPAD    64                   // padded T row length (halves) = 128 B
#define KSL     14                   // K-slices of 32 over 7*64 stacked T

#define NR    8                      // node ranges (LDS partitions)
#define RANGE (N_NODES / NR)         // 6250 counters
#define BPR   64                     // edge slices
#define SLICE (N_EDGES / BPR)        // 25000 edges per slice (div by 4)
#define HTHREADS 512
#define NBLK  ((N_NODES + 255) / 256)   // 196 reduce blocks
#define NTILES (N_NODES / 16)        // 3125 node tiles

typedef __attribute__((ext_vector_type(8))) _Float16 half8;
typedef __attribute__((ext_vector_type(4))) float f32x4;

// ---- gather+accumulate (lane<12 only), unroll-16 / 4 / scalar ----
#define PROP_GATHER_LOOP(TSRC)                                                  \
    {                                                                           \
        int e16 = s + ((e - s) & ~15);                                          \
        for (; p < e16; p += 16) {                                              \
            float ww[16]; uint2 hv[16];                                         \
            _Pragma("unroll")                                                   \
            for (int j = 0; j < 16; ++j) {                                      \
                uint2 er = edges[p + j];                                        \
                ww[j] = __uint_as_float(er.y);                                  \
                hv[j] = *reinterpret_cast<const uint2*>(                        \
                    TSRC + (size_t)er.x * TPAD + 4 * lane);                     \
            }                                                                   \
            _Pragma("unroll")                                                   \
            for (int j = 0; j < 16; ++j) {                                      \
                __half2 h01 = *reinterpret_cast<__half2*>(&hv[j].x);            \
                __half2 h23 = *reinterpret_cast<__half2*>(&hv[j].y);            \
                a0 += ww[j] * __low2float(h01);                                 \
                a1 += ww[j] * __high2float(h01);                                \
                a2 += ww[j] * __low2float(h23);                                 \
                a3 += ww[j] * __high2float(h23);                                \
            }                                                                   \
        }                                                                       \
        int e4b = p + ((e - p) & ~3);                                           \
        for (; p < e4b; p += 4) {                                               \
            float ww[4]; uint2 hv[4];                                           \
            _Pragma("unroll")                                                   \
            for (int j = 0; j < 4; ++j) {                                       \
                uint2 er = edges[p + j];                                        \
                ww[j] = __uint_as_float(er.y);                                  \
                hv[j] = *reinterpret_cast<const uint2*>(                        \
                    TSRC + (size_t)er.x * TPAD + 4 * lane);                     \
            }                                                                   \
            _Pragma("unroll")                                                   \
            for (int j = 0; j < 4; ++j) {                                       \
                __half2 h01 = *reinterpret_cast<__half2*>(&hv[j].x);            \
                __half2 h23 = *reinterpret_cast<__half2*>(&hv[j].y);            \
                a0 += ww[j] * __low2float(h01);                                 \
                a1 += ww[j] * __high2float(h01);                                \
                a2 += ww[j] * __low2float(h23);                                 \
                a3 += ww[j] * __high2float(h23);                                \
            }                                                                   \
        }                                                                       \
        for (; p < e; ++p) {                                                    \
            uint2 er = edges[p];                                                \
            float wv = __uint_as_float(er.y);                                   \
            uint2 hv = *reinterpret_cast<const uint2*>(                         \
                TSRC + (size_t)er.x * TPAD + 4 * lane);                         \
            __half2 h01 = *reinterpret_cast<__half2*>(&hv.x);                   \
            __half2 h23 = *reinterpret_cast<__half2*>(&hv.y);                   \
            a0 += wv * __low2float(h01);                                        \
            a1 += wv * __high2float(h01);                                       \
            a2 += wv * __low2float(h23);                                        \
            a3 += wv * __high2float(h23);                                       \
        }                                                                       \
    }

// ---- pass A: partitioned LDS histogram; ALSO records per-edge rank (u16) ----
__global__ __launch_bounds__(HTHREADS) void hist_part_kernel(
    const int* __restrict__ row, const int* __restrict__ col,
    const float* __restrict__ w,
    unsigned short* __restrict__ pc, float* __restrict__ pd,
    unsigned short* __restrict__ rank16)
{
    __shared__ unsigned lc32[RANGE / 2];  // 12.5 KB
    __shared__ float    ld[RANGE];        // 25 KB
    int t = threadIdx.x;
    for (int i = t; i < RANGE / 2; i += HTHREADS) lc32[i] = 0u;
    for (int i = t; i < RANGE; i += HTHREADS) ld[i] = 0.f;
    __syncthreads();
    int r = blockIdx.x / BPR;        // node range
    int b = blockIdx.x % BPR;        // edge slice
    int base = r * RANGE;
    int lo = b * SLICE;
    for (int e0 = lo + t * 4; e0 < lo + SLICE; e0 += HTHREADS * 4) {
        int4   c4 = *(const int4*)&col[e0];
        int4   r4 = *(const int4*)&row[e0];
        float4 w4 = *(const float4*)&w[e0];
        #pragma unroll
        for (int j = 0; j < 4; ++j) {
            int c  = (j == 0) ? c4.x : (j == 1) ? c4.y : (j == 2) ? c4.z : c4.w;
            int rw = (j == 0) ? r4.x : (j == 1) ? r4.y : (j == 2) ? r4.z : r4.w;
            float we = (j == 0) ? w4.x : (j == 1) ? w4.y : (j == 2) ? w4.z : w4.w;
            int ci = c - base;
            if ((unsigned)ci < RANGE) {
                unsigned sh = (ci & 1) * 16;
                unsigned old = atomicAdd(&lc32[ci >> 1], 1u << sh);
                rank16[e0 + j] = (unsigned short)((old >> sh) & 0xFFFFu);
            }
            int ri = rw - base;
            if ((unsigned)ri < RANGE) atomicAdd(&ld[ri], we);
        }
    }
    __syncthreads();
    unsigned short* pcb = pc + (size_t)blockIdx.x * RANGE;
    float*          pdb = pd + (size_t)blockIdx.x * RANGE;
    for (int i = t; i < RANGE; i += HTHREADS) {
        pcb[i] = (unsigned short)((lc32[i >> 1] >> ((i & 1) * 16)) & 0xFFFFu);
        pdb[i] = ld[i];
    }
}

// ---- fold partials: dinv, per-slice prefix (pc in place), intra-block scan ----
__global__ __launch_bounds__(256) void reduce_kernel(
    unsigned short* __restrict__ pc, const float* __restrict__ pd,
    float* __restrict__ dinv, int* __restrict__ off, int* __restrict__ bsum)
{
    int t = threadIdx.x;
    int n = blockIdx.x * 256 + t;
    int c = 0; float d = 0.f;
    if (n < N_NODES) {
        int r = n / RANGE, i = n - r * RANGE;
        size_t base = (size_t)r * BPR * RANGE + i;
        unsigned csum = 0;
        for (int b = 0; b < BPR; ++b) {
            size_t idx = base + (size_t)b * RANGE;
            unsigned x = pc[idx];
            pc[idx] = (unsigned short)csum;
            csum += x;
            d += pd[idx];
        }
        c = (int)csum;
        dinv[n] = d > 0.f ? rsqrtf(d) : 0.f;
    }
    int lane = t & 63, wid = t >> 6;
    int v = c;
    for (int s = 1; s < 64; s <<= 1) {
        int u = __shfl_up(v, s);
        if (lane >= s) v += u;
    }
    __shared__ int ws[4];
    if (lane == 63) ws[wid] = v;
    __syncthreads();
    int wb = 0;
    for (int i = 0; i < 4; ++i) if (i < wid) wb += ws[i];
    int ex = (v - c) + wb;
    if (n < N_NODES) off[n] = ex;
    if (t == 255) bsum[blockIdx.x] = ex + c;
}

// ---- exclusive scan of 196 block sums ----
__global__ __launch_bounds__(256) void bsum_scan_kernel(
    int* __restrict__ bsum, int* __restrict__ off)
{
    int t = threadIdx.x;
    int orig = (t < NBLK) ? bsum[t] : 0;
    int lane = t & 63, wid = t >> 6;
    int v = orig;
    for (int s = 1; s < 64; s <<= 1) {
        int u = __shfl_up(v, s);
        if (lane >= s) v += u;
    }
    __shared__ int ws[4];
    if (lane == 63) ws[wid] = v;
    __syncthreads();
    int wb = 0;
    for (int i = 0; i < 4; ++i) if (i < wid) wb += ws[i];
    int ex = (v - orig) + wb;
    if (t < NBLK) bsum[t] = ex;
    if (t == NBLK - 1) off[N_NODES] = ex + orig;
}

// ---- add block prefix back ----
__global__ __launch_bounds__(256) void add_off_kernel(
    int* __restrict__ off, const int* __restrict__ bsum)
{
    int n = blockIdx.x * 256 + threadIdx.x;
    if (n < N_NODES) off[n] += bsum[n >> 8];
}

// ---- flat scatter: ONE pass over edges using saved rank16 ----
__global__ __launch_bounds__(256) void scatter_flat_kernel(
    const int* __restrict__ row, const int* __restrict__ col,
    const float* __restrict__ w, const float* __restrict__ dinv,
    const int* __restrict__ off, const unsigned short* __restrict__ pc,
    const unsigned short* __restrict__ rank16, uint2* __restrict__ edges)
{
    int tid = blockIdx.x * 256 + threadIdx.x;
    int e0 = tid * 4;
    if (e0 >= N_EDGES) return;
    int b = e0 / SLICE;
    int4   c4 = *(const int4*)&col[e0];
    int4   r4 = *(const int4*)&row[e0];
    float4 w4 = *(const float4*)&w[e0];
    ushort4 k4 = *(const ushort4*)&rank16[e0];
    #pragma unroll
    for (int j = 0; j < 4; ++j) {
        int c  = (j == 0) ? c4.x : (j == 1) ? c4.y : (j == 2) ? c4.z : c4.w;
        int rw = (j == 0) ? r4.x : (j == 1) ? r4.y : (j == 2) ? r4.z : r4.w;
        float we = (j == 0) ? w4.x : (j == 1) ? w4.y : (j == 2) ? w4.z : w4.w;
        int rk = (j == 0) ? k4.x : (j == 1) ? k4.y : (j == 2) ? k4.z : k4.w;
        int rg = c / RANGE;
        int clocal = c - rg * RANGE;
        int pre = pc[(size_t)(rg * BPR + b) * RANGE + clocal];
        float nr = -dinv[rw] * we * dinv[c];
        int pos = off[c] + pre + rk;
        edges[pos] = make_uint2((unsigned)rw, __float_as_uint(nr));
    }
}

// ---- MFMA xf: xf = relu(x @ W_in + b_in) -> f32 d_out tail + padded fp16 T0 ----
__global__ __launch_bounds__(256) void xf_mfma_kernel(
    const float* __restrict__ x, const float* __restrict__ Win,
    const float* __restrict__ bin, float* __restrict__ xf_out,
    __half* __restrict__ T0h)
{
    __shared__ half8 Wf[3][4][64];   // 12288 B
    __shared__ float bs[EMB];
    int t = threadIdx.x;
    for (int idx = t; idx < 3 * 4 * 64; idx += 256) {
        int j = idx >> 8;
        int rem = idx & 255;
        int s = rem >> 6;
        int l = rem & 63;
        int colw = j * 16 + (l & 15);
        int k0 = s * 32 + (l >> 4) * 8;
        half8 v;
        #pragma unroll
        for (int i = 0; i < 8; ++i)
            v[i] = (_Float16)Win[(k0 + i) * EMB + colw];
        Wf[j][s][l] = v;
    }
    if (t < EMB) bs[t] = bin[t];
    __syncthreads();

    int wid = t >> 6, lane = t & 63;
    int nt = blockIdx.x * 4 + wid;
    if (nt >= NTILES) return;
    int n0 = nt * 16;
    int arow = lane & 15, kg = lane >> 4;

    const float* xr = x + (size_t)(n0 + arow) * F_IN + kg * 8;
    half8 a[4];
    #pragma unroll
    for (int s = 0; s < 4; ++s) {
        f32x4 lo = *reinterpret_cast<const f32x4*>(xr + s * 32);
        f32x4 hi = *reinterpret_cast<const f32x4*>(xr + s * 32 + 4);
        half8 av;
        av[0] = (_Float16)lo[0]; av[1] = (_Float16)lo[1];
        av[2] = (_Float16)lo[2]; av[3] = (_Float16)lo[3];
        av[4] = (_Float16)hi[0]; av[5] = (_Float16)hi[1];
        av[6] = (_Float16)hi[2]; av[7] = (_Float16)hi[3];
        a[s] = av;
    }

    f32x4 c0 = {0.f, 0.f, 0.f, 0.f}, c1 = c0, c2 = c0;
    #pragma unroll
    for (int s = 0; s < 4; ++s) {
        c0 = __builtin_amdgcn_mfma_f32_16x16x32_f16(a[s], Wf[0][s][lane], c0, 0, 0, 0);
        c1 = __builtin_amdgcn_mfma_f32_16x16x32_f16(a[s], Wf[1][s][lane], c1, 0, 0, 0);
        c2 = __builtin_amdgcn_mfma_f32_16x16x32_f16(a[s], Wf[2][s][lane], c2, 0, 0, 0);
    }

    int ccol = lane & 15;
    #pragma unroll
    for (int j = 0; j < 3; ++j) {
        int colg = j * 16 + ccol;
        float bias = bs[colg];
        f32x4 cj = (j == 0) ? c0 : (j == 1) ? c1 : c2;
        #pragma unroll
        for (int r = 0; r < 4; ++r) {
            int n = n0 + kg * 4 + r;
            float v = fmaxf(cj[r] + bias, 0.f);
            xf_out[(size_t)n * EMB + colg] = v;
            T0h[(size_t)n * TPAD + colg] = __float2half_rn(v);
        }
    }
    {
        int n = n0 + (lane >> 2);
        int cp = 48 + (lane & 3) * 4;
        *reinterpret_cast<uint2*>(T0h + (size_t)n * TPAD + cp) = make_uint2(0u, 0u);
    }
}

// ---- pure prop: tdst = prop(tsrc) [mode 0] or 2*prop(tsrc) - tprev [mode 1] ----
// No LDS, no epilogue — max occupancy for latency hiding.
__global__ __launch_bounds__(256) void prop_pure_kernel(
    const int* __restrict__ off, const uint2* __restrict__ edges,
    const __half* __restrict__ tsrc, const __half* __restrict__ tprev,
    __half* __restrict__ tdst, int cheb_mode)
{
    int t = threadIdx.x;
    int grp = t >> 4, lane = t & 15;
    int g = blockIdx.x * 16 + grp;

    float a0 = 0.f, a1 = 0.f, a2 = 0.f, a3 = 0.f;
    if (lane < 12) {
        int s = off[g], e = off[g + 1];
        int p = s;
        PROP_GATHER_LOOP(tsrc)
        if (cheb_mode) {
            uint2 tv = *reinterpret_cast<const uint2*>(tprev + (size_t)g * TPAD + 4 * lane);
            __half2 t01 = *reinterpret_cast<__half2*>(&tv.x);
            __half2 t23 = *reinterpret_cast<__half2*>(&tv.y);
            a0 = 2.f * a0 - __low2float(t01);
            a1 = 2.f * a1 - __high2float(t01);
            a2 = 2.f * a2 - __low2float(t23);
            a3 = 2.f * a3 - __high2float(t23);
        }
    }
    __half2 h01, h23;
    h01.x = __float2half_rn(a0); h01.y = __float2half_rn(a1);
    h23.x = __float2half_rn(a2); h23.y = __float2half_rn(a3);
    uint2 ov;
    ov.x = *reinterpret_cast<unsigned*>(&h01);
    ov.y = *reinterpret_cast<unsigned*>(&h23);
    *reinterpret_cast<uint2*>(tdst + (size_t)g * TPAD + 4 * lane) = ov;
}

// ---- MFMA epilogue: out = sum_k T_k @ W_k ; y = relu(out + bch) @ W_out + bout ----
// Stacked GEMM over K = 7*64 (pads zero), then second MFMA GEMM via LDS tile.
__global__ __launch_bounds__(256) void cheb_epi_kernel(
    const __half* __restrict__ Tall,   // [7][N_NODES*TPAD]
    const float* __restrict__ Wch,     // [7][48][48]
    const float* __restrict__ bch,
    const float* __restrict__ Wout,    // [48][64]
    const float* __restrict__ bout,
    float* __restrict__ y)
{
    __shared__ half8 Wf[3][KSL][64];      // 43008 B
    __shared__ half8 Wo[4][2][64];        // 8192 B
    __shared__ _Float16 vSh[4][16][64];   // 8192 B
    __shared__ float bchS[HID];
    __shared__ float boS[OUTF];
    int t = threadIdx.x;
    for (int idx = t; idx < 3 * KSL * 64; idx += 256) {
        int j = idx / (KSL * 64);
        int rem = idx - j * (KSL * 64);
        int s = rem >> 6;
        int l = rem & 63;
        int colw = j * 16 + (l & 15);
        int kch = s >> 1;
        int kbase = (s & 1) * 32 + (l >> 4) * 8;
        half8 v;
        #pragma unroll
        for (int i = 0; i < 8; ++i) {
            int kloc = kbase + i;
            v[i] = (kloc < EMB)
                 ? (_Float16)Wch[(size_t)kch * EMB * HID + kloc * HID + colw]
                 : (_Float16)0.f;
        }
        Wf[j][s][l] = v;
    }
    for (int idx = t; idx < 4 * 2 * 64; idx += 256) {
        int jo = idx >> 7;
        int rem = idx & 127;
        int so = rem >> 6;
        int l = rem & 63;
        int colw = jo * 16 + (l & 15);
        int kbase = so * 32 + (l >> 4) * 8;
        half8 v;
        #pragma unroll
        for (int i = 0; i < 8; ++i) {
            int kloc = kbase + i;
            v[i] = (kloc < HID) ? (_Float16)Wout[kloc * OUTF + colw] : (_Float16)0.f;
        }
        Wo[jo][so][l] = v;
    }
    if (t < HID) bchS[t] = bch[t];
    if (t < OUTF) boS[t] = bout[t];
    __syncthreads();

    int wid = t >> 6, lane = t & 63;
    int nt = blockIdx.x * 4 + wid;
    if (nt >= NTILES) return;
    int n0 = nt * 16;
    int arow = lane & 15, kg = lane >> 4;
    int ccol = lane & 15;

    f32x4 c0 = {0.f, 0.f, 0.f, 0.f}, c1 = c0, c2 = c0;
    #pragma unroll
    for (int s = 0; s < KSL; ++s) {
        const __half* tp = Tall + (size_t)(s >> 1) * N_NODES * TPAD
                         + (size_t)(n0 + arow) * TPAD + (s & 1) * 32 + kg * 8;
        half8 af = *reinterpret_cast<const half8*>(tp);
        c0 = __builtin_amdgcn_mfma_f32_16x16x32_f16(af, Wf[0][s][lane], c0, 0, 0, 0);
        c1 = __builtin_amdgcn_mfma_f32_16x16x32_f16(af, Wf[1][s][lane], c1, 0, 0, 0);
        c2 = __builtin_amdgcn_mfma_f32_16x16x32_f16(af, Wf[2][s][lane], c2, 0, 0, 0);
    }
    // v = relu(c + bch) -> per-wave LDS tile (f16, pad cols zero)
    #pragma unroll
    for (int j = 0; j < 3; ++j) {
        int colg = j * 16 + ccol;
        float bias = bchS[colg];
        f32x4 cj = (j == 0) ? c0 : (j == 1) ? c1 : c2;
        #pragma unroll
        for (int r = 0; r < 4; ++r)
            vSh[wid][kg * 4 + r][colg] = (_Float16)fmaxf(cj[r] + bias, 0.f);
    }
    {
        int rr = lane >> 2;
        int cp = 48 + (lane & 3) * 4;
        *reinterpret_cast<uint2*>(&vSh[wid][rr][cp]) = make_uint2(0u, 0u);
    }
    __builtin_amdgcn_wave_barrier();   // order LDS write -> read (same wave)

    f32x4 y0 = {0.f, 0.f, 0.f, 0.f}, y1 = y0, y2 = y0, y3 = y0;
    #pragma unroll
    for (int so = 0; so < 2; ++so) {
        half8 af = *reinterpret_cast<const half8*>(&vSh[wid][arow][so * 32 + kg * 8]);
        y0 = __builtin_amdgcn_mfma_f32_16x16x32_f16(af, Wo[0][so][lane], y0, 0, 0, 0);
        y1 = __builtin_amdgcn_mfma_f32_16x16x32_f16(af, Wo[1][so][lane], y1, 0, 0, 0);
        y2 = __builtin_amdgcn_mfma_f32_16x16x32_f16(af, Wo[2][so][lane], y2, 0, 0, 0);
        y3 = __builtin_amdgcn_mfma_f32_16x16x32_f16(af, Wo[3][so][lane], y3, 0, 0, 0);
    }
    #pragma unroll
    for (int jo = 0; jo < 4; ++jo) {
        int colg = jo * 16 + ccol;
        float bias = boS[colg];
        f32x4 cj = (jo == 0) ? y0 : (jo == 1) ? y1 : (jo == 2) ? y2 : y3;
        #pragma unroll
        for (int r = 0; r < 4; ++r)
            y[(size_t)(n0 + kg * 4 + r) * OUTF + colg] = cj[r] + bias;
    }
}

extern "C" void kernel_launch(void* const* d_in, const int* in_sizes, int n_in,
                              void* d_out, int out_size, void* d_ws, size_t ws_size,
                              hipStream_t stream)
{
    const float* x    = (const float*)d_in[0];
    const int*   ei   = (const int*)d_in[1];
    const float* ew   = (const float*)d_in[2];
    const float* Win  = (const float*)d_in[3];
    const float* bin  = (const float*)d_in[4];
    const float* Wch  = (const float*)d_in[5];   // [7,48,48]
    const float* bch  = (const float*)d_in[6];
    const float* Wout = (const float*)d_in[7];
    const float* bout = (const float*)d_in[8];

    const int* row = ei;
    const int* col = ei + N_EDGES;

    float* y_out  = (float*)d_out;                           // [N,64]
    float* xf_out = (float*)d_out + (size_t)N_NODES * OUTF;  // [N,48]

    char* p = (char*)d_ws;
    auto carve = [&](size_t bytes) {
        void* q = p;
        p += (bytes + 255) & ~(size_t)255;
        return q;
    };
    unsigned short* pc = (unsigned short*)carve((size_t)NR * BPR * RANGE * 2); // 6.4 MB
    float*    pd  = (float*)carve((size_t)NR * BPR * RANGE * 4);               // 12.8 MB
    unsigned short* rank16 = (unsigned short*)carve((size_t)N_EDGES * 2);      // 3.2 MB
    float*    dinv = (float*)carve(N_NODES * 4);
    int*      off  = (int*)  carve((N_NODES + 1) * 4);
    int*      bsum = (int*)  carve(NBLK * 4);
    uint2*    edges = (uint2*)carve((size_t)N_EDGES * 8);                      // 12.8 MB
    __half*   Tall = (__half*)carve((size_t)KCH * N_NODES * TPAD * 2);         // 44.8 MB

    // graph preprocessing — zero global atomics, single-pass flat scatter
    hist_part_kernel<<<NR * BPR, HTHREADS, 0, stream>>>(row, col, ew, pc, pd, rank16);
    reduce_kernel<<<NBLK, 256, 0, stream>>>(pc, pd, dinv, off, bsum);
    bsum_scan_kernel<<<1, 256, 0, stream>>>(bsum, off);
    add_off_kernel<<<NBLK, 256, 0, stream>>>(off, bsum);
    scatter_flat_kernel<<<(N_EDGES / 4 + 255) / 256, 256, 0, stream>>>(
        row, col, ew, dinv, off, pc, rank16, edges);

    // xf via MFMA -> f32 d_out tail + padded fp16 T0
    const size_t TSTR = (size_t)N_NODES * TPAD;
    xf_mfma_kernel<<<(NTILES + 3) / 4, 256, 0, stream>>>(x, Win, bin, xf_out, Tall);

    const int prop_grid = NTILES;   // 3125

    // T1 = prop(T0); Tk = 2*prop(T_{k-1}) - T_{k-2}, all pure
    prop_pure_kernel<<<prop_grid, 256, 0, stream>>>(off, edges, Tall, nullptr,
                                                    Tall + TSTR, 0);
    for (int k = 2; k < KCH; ++k) {
        prop_pure_kernel<<<prop_grid, 256, 0, stream>>>(
            off, edges, Tall + (size_t)(k - 1) * TSTR, Tall + (size_t)(k - 2) * TSTR,
            Tall + (size_t)k * TSTR, 1);
    }

    // out = sum_k Tk @ Wk ; y = relu(out + bch) @ Wout + bout (all-MFMA)
    cheb_epi_kernel<<<(NTILES + 3) / 4, 256, 0, stream>>>(Tall, Wch, bch, Wout, bout, y_out);
}

// Round 20
// 300.597 us; speedup vs baseline: 1.4373x; 1.0893x over previous
//
#include <hip/hip_runtime.h>
#include <hip/hip_fp16.h>

#define N_NODES 50000
#define N_EDGES 1600000
#define F_IN    128
#define EMB     48
#define HID     48
#define OUTF    64
#define KCH     7
#define TPAD    64                   // padded T row length (halves) = 128 B
#define KSL     14                   // K-slices of 32 over 7*64 stacked T

#define NR    8                      // node ranges (LDS partitions)
#define RANGE (N_NODES / NR)         // 6250 counters
#define BPR   64                     // edge slices
#define SLICE (N_EDGES / BPR)        // 25000 edges per slice (div by 4)
#define HTHREADS 512
#define NBLK  ((N_NODES + 255) / 256)   // 196 reduce blocks
#define NTILES (N_NODES / 16)        // 3125 node tiles

typedef __attribute__((ext_vector_type(8))) _Float16 half8;
typedef __attribute__((ext_vector_type(4))) float f32x4;

// ---- gather+accumulate (lane<12 only), unroll-16 / 4 / scalar ----
#define PROP_GATHER_LOOP(TSRC)                                                  \
    {                                                                           \
        int e16 = s + ((e - s) & ~15);                                          \
        for (; p < e16; p += 16) {                                              \
            float ww[16]; uint2 hv[16];                                         \
            _Pragma("unroll")                                                   \
            for (int j = 0; j < 16; ++j) {                                      \
                uint2 er = edges[p + j];                                        \
                ww[j] = __uint_as_float(er.y);                                  \
                hv[j] = *reinterpret_cast<const uint2*>(                        \
                    TSRC + (size_t)er.x * TPAD + 4 * lane);                     \
            }                                                                   \
            _Pragma("unroll")                                                   \
            for (int j = 0; j < 16; ++j) {                                      \
                __half2 h01 = *reinterpret_cast<__half2*>(&hv[j].x);            \
                __half2 h23 = *reinterpret_cast<__half2*>(&hv[j].y);            \
                a0 += ww[j] * __low2float(h01);                                 \
                a1 += ww[j] * __high2float(h01);                                \
                a2 += ww[j] * __low2float(h23);                                 \
                a3 += ww[j] * __high2float(h23);                                \
            }                                                                   \
        }                                                                       \
        int e4b = p + ((e - p) & ~3);                                           \
        for (; p < e4b; p += 4) {                                               \
            float ww[4]; uint2 hv[4];                                           \
            _Pragma("unroll")                                                   \
            for (int j = 0; j < 4; ++j) {                                       \
                uint2 er = edges[p + j];                                        \
                ww[j] = __uint_as_float(er.y);                                  \
                hv[j] = *reinterpret_cast<const uint2*>(                        \
                    TSRC + (size_t)er.x * TPAD + 4 * lane);                     \
            }                                                                   \
            _Pragma("unroll")                                                   \
            for (int j = 0; j < 4; ++j) {                                       \
                __half2 h01 = *reinterpret_cast<__half2*>(&hv[j].x);            \
                __half2 h23 = *reinterpret_cast<__half2*>(&hv[j].y);            \
                a0 += ww[j] * __low2float(h01);                                 \
                a1 += ww[j] * __high2float(h01);                                \
                a2 += ww[j] * __low2float(h23);                                 \
                a3 += ww[j] * __high2float(h23);                                \
            }                                                                   \
        }                                                                       \
        for (; p < e; ++p) {                                                    \
            uint2 er = edges[p];                                                \
            float wv = __uint_as_float(er.y);                                   \
            uint2 hv = *reinterpret_cast<const uint2*>(                         \
                TSRC + (size_t)er.x * TPAD + 4 * lane);                         \
            __half2 h01 = *reinterpret_cast<__half2*>(&hv.x);                   \
            __half2 h23 = *reinterpret_cast<__half2*>(&hv.y);                   \
            a0 += wv * __low2float(h01);                                        \
            a1 += wv * __high2float(h01);                                       \
            a2 += wv * __low2float(h23);                                        \
            a3 += wv * __high2float(h23);                                       \
        }                                                                       \
    }

// ---- pass A: partitioned LDS histogram; ALSO records per-edge rank (u16) ----
__global__ __launch_bounds__(HTHREADS) void hist_part_kernel(
    const int* __restrict__ row, const int* __restrict__ col,
    const float* __restrict__ w,
    unsigned short* __restrict__ pc, float* __restrict__ pd,
    unsigned short* __restrict__ rank16)
{
    __shared__ unsigned lc32[RANGE / 2];  // 12.5 KB
    __shared__ float    ld[RANGE];        // 25 KB
    int t = threadIdx.x;
    for (int i = t; i < RANGE / 2; i += HTHREADS) lc32[i] = 0u;
    for (int i = t; i < RANGE; i += HTHREADS) ld[i] = 0.f;
    __syncthreads();
    int r = blockIdx.x / BPR;        // node range
    int b = blockIdx.x % BPR;        // edge slice
    int base = r * RANGE;
    int lo = b * SLICE;
    for (int e0 = lo + t * 4; e0 < lo + SLICE; e0 += HTHREADS * 4) {
        int4   c4 = *(const int4*)&col[e0];
        int4   r4 = *(const int4*)&row[e0];
        float4 w4 = *(const float4*)&w[e0];
        #pragma unroll
        for (int j = 0; j < 4; ++j) {
            int c  = (j == 0) ? c4.x : (j == 1) ? c4.y : (j == 2) ? c4.z : c4.w;
            int rw = (j == 0) ? r4.x : (j == 1) ? r4.y : (j == 2) ? r4.z : r4.w;
            float we = (j == 0) ? w4.x : (j == 1) ? w4.y : (j == 2) ? w4.z : w4.w;
            int ci = c - base;
            if ((unsigned)ci < RANGE) {
                unsigned sh = (ci & 1) * 16;
                unsigned old = atomicAdd(&lc32[ci >> 1], 1u << sh);
                rank16[e0 + j] = (unsigned short)((old >> sh) & 0xFFFFu);
            }
            int ri = rw - base;
            if ((unsigned)ri < RANGE) atomicAdd(&ld[ri], we);
        }
    }
    __syncthreads();
    unsigned short* pcb = pc + (size_t)blockIdx.x * RANGE;
    float*          pdb = pd + (size_t)blockIdx.x * RANGE;
    for (int i = t; i < RANGE; i += HTHREADS) {
        pcb[i] = (unsigned short)((lc32[i >> 1] >> ((i & 1) * 16)) & 0xFFFFu);
        pdb[i] = ld[i];
    }
}

// ---- fold partials: dinv, per-slice prefix (pc in place), intra-block scan ----
__global__ __launch_bounds__(256) void reduce_kernel(
    unsigned short* __restrict__ pc, const float* __restrict__ pd,
    float* __restrict__ dinv, int* __restrict__ off, int* __restrict__ bsum)
{
    int t = threadIdx.x;
    int n = blockIdx.x * 256 + t;
    int c = 0; float d = 0.f;
    if (n < N_NODES) {
        int r = n / RANGE, i = n - r * RANGE;
        size_t base = (size_t)r * BPR * RANGE + i;
        unsigned csum = 0;
        for (int b = 0; b < BPR; ++b) {
            size_t idx = base + (size_t)b * RANGE;
            unsigned x = pc[idx];
            pc[idx] = (unsigned short)csum;
            csum += x;
            d += pd[idx];
        }
        c = (int)csum;
        dinv[n] = d > 0.f ? rsqrtf(d) : 0.f;
    }
    int lane = t & 63, wid = t >> 6;
    int v = c;
    for (int s = 1; s < 64; s <<= 1) {
        int u = __shfl_up(v, s);
        if (lane >= s) v += u;
    }
    __shared__ int ws[4];
    if (lane == 63) ws[wid] = v;
    __syncthreads();
    int wb = 0;
    for (int i = 0; i < 4; ++i) if (i < wid) wb += ws[i];
    int ex = (v - c) + wb;
    if (n < N_NODES) off[n] = ex;
    if (t == 255) bsum[blockIdx.x] = ex + c;
}

// ---- exclusive scan of 196 block sums ----
__global__ __launch_bounds__(256) void bsum_scan_kernel(
    int* __restrict__ bsum, int* __restrict__ off)
{
    int t = threadIdx.x;
    int orig = (t < NBLK) ? bsum[t] : 0;
    int lane = t & 63, wid = t >> 6;
    int v = orig;
    for (int s = 1; s < 64; s <<= 1) {
        int u = __shfl_up(v, s);
        if (lane >= s) v += u;
    }
    __shared__ int ws[4];
    if (lane == 63) ws[wid] = v;
    __syncthreads();
    int wb = 0;
    for (int i = 0; i < 4; ++i) if (i < wid) wb += ws[i];
    int ex = (v - orig) + wb;
    if (t < NBLK) bsum[t] = ex;
    if (t == NBLK - 1) off[N_NODES] = ex + orig;
}

// ---- add block prefix back ----
__global__ __launch_bounds__(256) void add_off_kernel(
    int* __restrict__ off, const int* __restrict__ bsum)
{
    int n = blockIdx.x * 256 + threadIdx.x;
    if (n < N_NODES) off[n] += bsum[n >> 8];
}

// ---- flat scatter: ONE pass over edges using saved rank16 ----
__global__ __launch_bounds__(256) void scatter_flat_kernel(
    const int* __restrict__ row, const int* __restrict__ col,
    const float* __restrict__ w, const float* __restrict__ dinv,
    const int* __restrict__ off, const unsigned short* __restrict__ pc,
    const unsigned short* __restrict__ rank16, uint2* __restrict__ edges)
{
    int tid = blockIdx.x * 256 + threadIdx.x;
    int e0 = tid * 4;
    if (e0 >= N_EDGES) return;
    int b = e0 / SLICE;
    int4   c4 = *(const int4*)&col[e0];
    int4   r4 = *(const int4*)&row[e0];
    float4 w4 = *(const float4*)&w[e0];
    ushort4 k4 = *(const ushort4*)&rank16[e0];
    #pragma unroll
    for (int j = 0; j < 4; ++j) {
        int c  = (j == 0) ? c4.x : (j == 1) ? c4.y : (j == 2) ? c4.z : c4.w;
        int rw = (j == 0) ? r4.x : (j == 1) ? r4.y : (j == 2) ? r4.z : r4.w;
        float we = (j == 0) ? w4.x : (j == 1) ? w4.y : (j == 2) ? w4.z : w4.w;
        int rk = (j == 0) ? k4.x : (j == 1) ? k4.y : (j == 2) ? k4.z : k4.w;
        int rg = c / RANGE;
        int clocal = c - rg * RANGE;
        int pre = pc[(size_t)(rg * BPR + b) * RANGE + clocal];
        float nr = -dinv[rw] * we * dinv[c];
        int pos = off[c] + pre + rk;
        edges[pos] = make_uint2((unsigned)rw, __float_as_uint(nr));
    }
}

// ---- MFMA xf: xf = relu(x @ W_in + b_in) -> f32 d_out tail + padded fp16 T0 ----
__global__ __launch_bounds__(256) void xf_mfma_kernel(
    const float* __restrict__ x, const float* __restrict__ Win,
    const float* __restrict__ bin, float* __restrict__ xf_out,
    __half* __restrict__ T0h)
{
    __shared__ half8 Wf[3][4][64];   // 12288 B
    __shared__ float bs[EMB];
    int t = threadIdx.x;
    for (int idx = t; idx < 3 * 4 * 64; idx += 256) {
        int j = idx >> 8;
        int rem = idx & 255;
        int s = rem >> 6;
        int l = rem & 63;
        int colw = j * 16 + (l & 15);
        int k0 = s * 32 + (l >> 4) * 8;
        half8 v;
        #pragma unroll
        for (int i = 0; i < 8; ++i)
            v[i] = (_Float16)Win[(k0 + i) * EMB + colw];
        Wf[j][s][l] = v;
    }
    if (t < EMB) bs[t] = bin[t];
    __syncthreads();

    int wid = t >> 6, lane = t & 63;
    int nt = blockIdx.x * 4 + wid;
    if (nt >= NTILES) return;
    int n0 = nt * 16;
    int arow = lane & 15, kg = lane >> 4;

    const float* xr = x + (size_t)(n0 + arow) * F_IN + kg * 8;
    half8 a[4];
    #pragma unroll
    for (int s = 0; s < 4; ++s) {
        f32x4 lo = *reinterpret_cast<const f32x4*>(xr + s * 32);
        f32x4 hi = *reinterpret_cast<const f32x4*>(xr + s * 32 + 4);
        half8 av;
        av[0] = (_Float16)lo[0]; av[1] = (_Float16)lo[1];
        av[2] = (_Float16)lo[2]; av[3] = (_Float16)lo[3];
        av[4] = (_Float16)hi[0]; av[5] = (_Float16)hi[1];
        av[6] = (_Float16)hi[2]; av[7] = (_Float16)hi[3];
        a[s] = av;
    }

    f32x4 c0 = {0.f, 0.f, 0.f, 0.f}, c1 = c0, c2 = c0;
    #pragma unroll
    for (int s = 0; s < 4; ++s) {
        c0 = __builtin_amdgcn_mfma_f32_16x16x32_f16(a[s], Wf[0][s][lane], c0, 0, 0, 0);
        c1 = __builtin_amdgcn_mfma_f32_16x16x32_f16(a[s], Wf[1][s][lane], c1, 0, 0, 0);
        c2 = __builtin_amdgcn_mfma_f32_16x16x32_f16(a[s], Wf[2][s][lane], c2, 0, 0, 0);
    }

    int ccol = lane & 15;
    #pragma unroll
    for (int j = 0; j < 3; ++j) {
        int colg = j * 16 + ccol;
        float bias = bs[colg];
        f32x4 cj = (j == 0) ? c0 : (j == 1) ? c1 : c2;
        #pragma unroll
        for (int r = 0; r < 4; ++r) {
            int n = n0 + kg * 4 + r;
            float v = fmaxf(cj[r] + bias, 0.f);
            xf_out[(size_t)n * EMB + colg] = v;
            T0h[(size_t)n * TPAD + colg] = __float2half_rn(v);
        }
    }
    {
        int n = n0 + (lane >> 2);
        int cp = 48 + (lane & 3) * 4;
        *reinterpret_cast<uint2*>(T0h + (size_t)n * TPAD + cp) = make_uint2(0u, 0u);
    }
}

// ---- pure prop: tdst = prop(tsrc) [mode 0] or 2*prop(tsrc) - tprev [mode 1] ----
__global__ __launch_bounds__(256) void prop_pure_kernel(
    const int* __restrict__ off, const uint2* __restrict__ edges,
    const __half* __restrict__ tsrc, const __half* __restrict__ tprev,
    __half* __restrict__ tdst, int cheb_mode)
{
    int t = threadIdx.x;
    int grp = t >> 4, lane = t & 15;
    int g = blockIdx.x * 16 + grp;

    float a0 = 0.f, a1 = 0.f, a2 = 0.f, a3 = 0.f;
    if (lane < 12) {
        int s = off[g], e = off[g + 1];
        int p = s;
        PROP_GATHER_LOOP(tsrc)
        if (cheb_mode) {
            uint2 tv = *reinterpret_cast<const uint2*>(tprev + (size_t)g * TPAD + 4 * lane);
            __half2 t01 = *reinterpret_cast<__half2*>(&tv.x);
            __half2 t23 = *reinterpret_cast<__half2*>(&tv.y);
            a0 = 2.f * a0 - __low2float(t01);
            a1 = 2.f * a1 - __high2float(t01);
            a2 = 2.f * a2 - __low2float(t23);
            a3 = 2.f * a3 - __high2float(t23);
        }
    }
    __half2 h01, h23;
    h01.x = __float2half_rn(a0); h01.y = __float2half_rn(a1);
    h23.x = __float2half_rn(a2); h23.y = __float2half_rn(a3);
    uint2 ov;
    ov.x = *reinterpret_cast<unsigned*>(&h01);
    ov.y = *reinterpret_cast<unsigned*>(&h23);
    *reinterpret_cast<uint2*>(tdst + (size_t)g * TPAD + 4 * lane) = ov;
}

// ---- out GEMM (MFMA): v = relu(sum_k T_k @ W_k + bch) -> padded f16 vAll ----
// 512 threads = 8 waves = 8 tiles/block; LDS = Wf only (43 KB) -> 3 blocks/CU.
__global__ __launch_bounds__(HTHREADS) void out_mfma_kernel(
    const __half* __restrict__ Tall, const float* __restrict__ Wch,
    const float* __restrict__ bch, __half* __restrict__ vAll)
{
    __shared__ half8 Wf[3][KSL][64];   // 43008 B
    __shared__ float bchS[HID];
    int t = threadIdx.x;
    for (int idx = t; idx < 3 * KSL * 64; idx += HTHREADS) {
        int j = idx / (KSL * 64);
        int rem = idx - j * (KSL * 64);
        int s = rem >> 6;
        int l = rem & 63;
        int colw = j * 16 + (l & 15);
        int kch = s >> 1;
        int kbase = (s & 1) * 32 + (l >> 4) * 8;
        half8 v;
        #pragma unroll
        for (int i = 0; i < 8; ++i) {
            int kloc = kbase + i;
            v[i] = (kloc < EMB)
                 ? (_Float16)Wch[(size_t)kch * EMB * HID + kloc * HID + colw]
                 : (_Float16)0.f;
        }
        Wf[j][s][l] = v;
    }
    if (t < HID) bchS[t] = bch[t];
    __syncthreads();

    int wid = t >> 6, lane = t & 63;
    int nt = blockIdx.x * 8 + wid;
    if (nt >= NTILES) return;
    int n0 = nt * 16;
    int arow = lane & 15, kg = lane >> 4;
    int ccol = lane & 15;

    f32x4 c0 = {0.f, 0.f, 0.f, 0.f}, c1 = c0, c2 = c0;
    #pragma unroll
    for (int s = 0; s < KSL; ++s) {
        const __half* tp = Tall + (size_t)(s >> 1) * N_NODES * TPAD
                         + (size_t)(n0 + arow) * TPAD + (s & 1) * 32 + kg * 8;
        half8 af = *reinterpret_cast<const half8*>(tp);
        c0 = __builtin_amdgcn_mfma_f32_16x16x32_f16(af, Wf[0][s][lane], c0, 0, 0, 0);
        c1 = __builtin_amdgcn_mfma_f32_16x16x32_f16(af, Wf[1][s][lane], c1, 0, 0, 0);
        c2 = __builtin_amdgcn_mfma_f32_16x16x32_f16(af, Wf[2][s][lane], c2, 0, 0, 0);
    }
    #pragma unroll
    for (int j = 0; j < 3; ++j) {
        int colg = j * 16 + ccol;
        float bias = bchS[colg];
        f32x4 cj = (j == 0) ? c0 : (j == 1) ? c1 : c2;
        #pragma unroll
        for (int r = 0; r < 4; ++r)
            vAll[(size_t)(n0 + kg * 4 + r) * TPAD + colg] =
                __float2half_rn(fmaxf(cj[r] + bias, 0.f));
    }
    {
        int n = n0 + (lane >> 2);
        int cp = 48 + (lane & 3) * 4;
        *reinterpret_cast<uint2*>(vAll + (size_t)n * TPAD + cp) = make_uint2(0u, 0u);
    }
}

// ---- y GEMM (MFMA): y = vAll @ W_out + bout ----
__global__ __launch_bounds__(HTHREADS) void y_mfma_kernel(
    const __half* __restrict__ vAll, const float* __restrict__ Wout,
    const float* __restrict__ bout, float* __restrict__ y)
{
    __shared__ half8 Wo[4][2][64];   // 8192 B
    __shared__ float boS[OUTF];
    int t = threadIdx.x;
    for (int idx = t; idx < 4 * 2 * 64; idx += HTHREADS) {
        int jo = idx >> 7;
        int rem = idx & 127;
        int so = rem >> 6;
        int l = rem & 63;
        int colw = jo * 16 + (l & 15);
        int kbase = so * 32 + (l >> 4) * 8;
        half8 v;
        #pragma unroll
        for (int i = 0; i < 8; ++i) {
            int kloc = kbase + i;
            v[i] = (kloc < HID) ? (_Float16)Wout[kloc * OUTF + colw] : (_Float16)0.f;
        }
        Wo[jo][so][l] = v;
    }
    if (t < OUTF) boS[t] = bout[t];
    __syncthreads();

    int wid = t >> 6, lane = t & 63;
    int nt = blockIdx.x * 8 + wid;
    if (nt >= NTILES) return;
    int n0 = nt * 16;
    int arow = lane & 15, kg = lane >> 4;
    int ccol = lane & 15;

    f32x4 y0 = {0.f, 0.f, 0.f, 0.f}, y1 = y0, y2 = y0, y3 = y0;
    #pragma unroll
    for (int so = 0; so < 2; ++so) {
        half8 af = *reinterpret_cast<const half8*>(
            vAll + (size_t)(n0 + arow) * TPAD + so * 32 + kg * 8);
        y0 = __builtin_amdgcn_mfma_f32_16x16x32_f16(af, Wo[0][so][lane], y0, 0, 0, 0);
        y1 = __builtin_amdgcn_mfma_f32_16x16x32_f16(af, Wo[1][so][lane], y1, 0, 0, 0);
        y2 = __builtin_amdgcn_mfma_f32_16x16x32_f16(af, Wo[2][so][lane], y2, 0, 0, 0);
        y3 = __builtin_amdgcn_mfma_f32_16x16x32_f16(af, Wo[3][so][lane], y3, 0, 0, 0);
    }
    #pragma unroll
    for (int jo = 0; jo < 4; ++jo) {
        int colg = jo * 16 + ccol;
        float bias = boS[colg];
        f32x4 cj = (jo == 0) ? y0 : (jo == 1) ? y1 : (jo == 2) ? y2 : y3;
        #pragma unroll
        for (int r = 0; r < 4; ++r)
            y[(size_t)(n0 + kg * 4 + r) * OUTF + colg] = cj[r] + bias;
    }
}

extern "C" void kernel_launch(void* const* d_in, const int* in_sizes, int n_in,
                              void* d_out, int out_size, void* d_ws, size_t ws_size,
                              hipStream_t stream)
{
    const float* x    = (const float*)d_in[0];
    const int*   ei   = (const int*)d_in[1];
    const float* ew   = (const float*)d_in[2];
    const float* Win  = (const float*)d_in[3];
    const float* bin  = (const float*)d_in[4];
    const float* Wch  = (const float*)d_in[5];   // [7,48,48]
    const float* bch  = (const float*)d_in[6];
    const float* Wout = (const float*)d_in[7];
    const float* bout = (const float*)d_in[8];

    const int* row = ei;
    const int* col = ei + N_EDGES;

    float* y_out  = (float*)d_out;                           // [N,64]
    float* xf_out = (float*)d_out + (size_t)N_NODES * OUTF;  // [N,48]

    char* p = (char*)d_ws;
    auto carve = [&](size_t bytes) {
        void* q = p;
        p += (bytes + 255) & ~(size_t)255;
        return q;
    };
    unsigned short* pc = (unsigned short*)carve((size_t)NR * BPR * RANGE * 2); // 6.4 MB
    float*    pd  = (float*)carve((size_t)NR * BPR * RANGE * 4);               // 12.8 MB
    unsigned short* rank16 = (unsigned short*)carve((size_t)N_EDGES * 2);      // 3.2 MB
    float*    dinv = (float*)carve(N_NODES * 4);
    int*      off  = (int*)  carve((N_NODES + 1) * 4);
    int*      bsum = (int*)  carve(NBLK * 4);
    uint2*    edges = (uint2*)carve((size_t)N_EDGES * 8);                      // 12.8 MB
    __half*   Tall = (__half*)carve((size_t)KCH * N_NODES * TPAD * 2);         // 44.8 MB
    __half*   vAll = (__half*)carve((size_t)N_NODES * TPAD * 2);               // 6.4 MB

    // graph preprocessing — zero global atomics, single-pass flat scatter
    hist_part_kernel<<<NR * BPR, HTHREADS, 0, stream>>>(row, col, ew, pc, pd, rank16);
    reduce_kernel<<<NBLK, 256, 0, stream>>>(pc, pd, dinv, off, bsum);
    bsum_scan_kernel<<<1, 256, 0, stream>>>(bsum, off);
    add_off_kernel<<<NBLK, 256, 0, stream>>>(off, bsum);
    scatter_flat_kernel<<<(N_EDGES / 4 + 255) / 256, 256, 0, stream>>>(
        row, col, ew, dinv, off, pc, rank16, edges);

    // xf via MFMA -> f32 d_out tail + padded fp16 T0
    const size_t TSTR = (size_t)N_NODES * TPAD;
    xf_mfma_kernel<<<(NTILES + 3) / 4, 256, 0, stream>>>(x, Win, bin, xf_out, Tall);

    const int prop_grid = NTILES;   // 3125

    // T1 = prop(T0); Tk = 2*prop(T_{k-1}) - T_{k-2}, all pure
    prop_pure_kernel<<<prop_grid, 256, 0, stream>>>(off, edges, Tall, nullptr,
                                                    Tall + TSTR, 0);
    for (int k = 2; k < KCH; ++k) {
        prop_pure_kernel<<<prop_grid, 256, 0, stream>>>(
            off, edges, Tall + (size_t)(k - 1) * TSTR, Tall + (size_t)(k - 2) * TSTR,
            Tall + (size_t)k * TSTR, 1);
    }

    // v = relu(sum_k Tk @ Wk + bch); y = v @ Wout + bout (all-MFMA, split for occupancy)
    out_mfma_kernel<<<(NTILES + 7) / 8, HTHREADS, 0, stream>>>(Tall, Wch, bch, vAll);
    y_mfma_kernel<<<(NTILES + 7) / 8, HTHREADS, 0, stream>>>(vAll, Wout, bout, y_out);
}